// Round 6
// baseline (296.727 us; speedup 1.0000x reference)
//
#include <hip/hip_runtime.h>

// ---------------------------------------------------------------------------
// Problem constants
#define BQ 2048
#define NS 32768
#define DIM 256
#define NROWS (NS + BQ)

// Fast-path (MFMA) tiling
#define BM 128                 // queries per block
#define BN 128                 // supports per inner tile
#define BK 32                  // K per stage (= one 16x16x32 MFMA K)
#define NTILES 4               // support tiles per block (R6: 8->4, grid 512->1024)
#define CHUNK (BN * NTILES)    // 512 supports per block
#define GY (NS / CHUNK)        // 64 chunks
#define LDK (BK + 8)           // 40 f16 row stride = 80 B: 16B-aligned rows,
                               // b128 frag reads land exactly 8 words/bank (floor)
#define EPS 2e-3f              // certified-gap threshold (>10x split error bound)
#define FBCH 32                // fallback chunks per query (1024 rows each)

typedef _Float16 f16;
typedef _Float16 f16x4 __attribute__((ext_vector_type(4)));
typedef _Float16 f16x8 __attribute__((ext_vector_type(8)));
typedef float    f32x4 __attribute__((ext_vector_type(4)));

// ---------------------------------------------------------------------------
// Fast path kernel 1: split fp32 -> (hi,lo) f16 for x and support; s2 exact
// fp32. One wave per row, 4 rows per block. Block 0 thread 0 zeroes fb_cnt.
// ---------------------------------------------------------------------------
__global__ __launch_bounds__(256) void convert_kernel(
    const float* __restrict__ x, const float* __restrict__ sup,
    f16* __restrict__ xh, f16* __restrict__ xl,
    f16* __restrict__ sh, f16* __restrict__ sl,
    float* __restrict__ s2, int* __restrict__ fb_cnt) {
    if (blockIdx.x == 0 && threadIdx.x == 0) *fb_cnt = 0;
    const int wave = threadIdx.x >> 6, lane = threadIdx.x & 63;
    const int row = blockIdx.x * 4 + wave;
    const float* src;
    f16 *dh, *dl;
    const bool issup = row < NS;
    if (issup) {
        src = sup + (size_t)row * DIM;
        dh = sh + (size_t)row * DIM; dl = sl + (size_t)row * DIM;
    } else {
        const int q = row - NS;
        src = x + (size_t)q * DIM;
        dh = xh + (size_t)q * DIM; dl = xl + (size_t)q * DIM;
    }
    float4 v = ((const float4*)src)[lane];
    f16x4 hi, lo;
    hi[0] = (f16)v.x; lo[0] = (f16)(v.x - (float)hi[0]);
    hi[1] = (f16)v.y; lo[1] = (f16)(v.y - (float)hi[1]);
    hi[2] = (f16)v.z; lo[2] = (f16)(v.z - (float)hi[2]);
    hi[3] = (f16)v.w; lo[3] = (f16)(v.w - (float)hi[3]);
    *(f16x4*)(dh + lane * 4) = hi;
    *(f16x4*)(dl + lane * 4) = lo;
    if (issup) {
        float sum = v.x * v.x + v.y * v.y + v.z * v.z + v.w * v.w;
#pragma unroll
        for (int off = 32; off > 0; off >>= 1) sum += __shfl_xor(sum, off);
        if (lane == 0) s2[row] = sum;
    }
}

// ---------------------------------------------------------------------------
// Fast path kernel 2: fused split-f16 MFMA GEMM + certified top-2 argmin.
// R6: b128 LDS fragment reads (was 2x b64 — 2x instr count + bank clustering),
// b128 staging stores, NTILES 8->4 so grid=1024 (4 blocks/CU, was 2).
// ---------------------------------------------------------------------------
__global__ __launch_bounds__(256) void knn_mfma(
    const f16* __restrict__ xh, const f16* __restrict__ xl,
    const f16* __restrict__ sh, const f16* __restrict__ sl,
    const float* __restrict__ s2g,
    float* __restrict__ pv1, float* __restrict__ pv2, int* __restrict__ pi1) {
    __shared__ __align__(16) f16 Xh[BM][LDK], Xl[BM][LDK], Sh[BN][LDK], Sl[BN][LDK];

    const int tid  = threadIdx.x;
    const int lane = tid & 63, wid = tid >> 6;
    const int l16  = lane & 15, quad = lane >> 4;
    const int q8   = quad * 8;
    const int m0   = blockIdx.x * BM;
    const int c0   = blockIdx.y * CHUNK;

    const int srow  = tid >> 1;          // staging: 2 threads/row
    const int shalf = (tid & 1) * 16;    // each covers 16 f16 (32 B)

    float v1[8], v2[8]; int i1[8];
#pragma unroll
    for (int s = 0; s < 8; ++s) { v1[s] = 3.4e38f; v2[s] = 3.4e38f; i1[s] = 0x7fffffff; }

    for (int nt = 0; nt < NTILES; ++nt) {
        const int n0 = c0 + nt * BN;
        f32x4 acc[2][8];
#pragma unroll
        for (int fi = 0; fi < 2; ++fi)
#pragma unroll
            for (int fj = 0; fj < 8; ++fj) acc[fi][fj] = (f32x4){0.f, 0.f, 0.f, 0.f};

        for (int kt = 0; kt < DIM / BK; ++kt) {
            const int k0 = kt * BK;
            const size_t xo = (size_t)(m0 + srow) * DIM + k0 + shalf;
            const size_t so = (size_t)(n0 + srow) * DIM + k0 + shalf;
            float4 vxh0 = *(const float4*)(xh + xo);
            float4 vxh1 = *(const float4*)(xh + xo + 8);
            float4 vxl0 = *(const float4*)(xl + xo);
            float4 vxl1 = *(const float4*)(xl + xo + 8);
            float4 vsh0 = *(const float4*)(sh + so);
            float4 vsh1 = *(const float4*)(sh + so + 8);
            float4 vsl0 = *(const float4*)(sl + so);
            float4 vsl1 = *(const float4*)(sl + so + 8);
            __syncthreads();                      // prior iteration's reads done
            *(f16x8*)&Xh[srow][shalf]     = *(const f16x8*)&vxh0;
            *(f16x8*)&Xh[srow][shalf + 8] = *(const f16x8*)&vxh1;
            *(f16x8*)&Xl[srow][shalf]     = *(const f16x8*)&vxl0;
            *(f16x8*)&Xl[srow][shalf + 8] = *(const f16x8*)&vxl1;
            *(f16x8*)&Sh[srow][shalf]     = *(const f16x8*)&vsh0;
            *(f16x8*)&Sh[srow][shalf + 8] = *(const f16x8*)&vsh1;
            *(f16x8*)&Sl[srow][shalf]     = *(const f16x8*)&vsl0;
            *(f16x8*)&Sl[srow][shalf + 8] = *(const f16x8*)&vsl1;
            __syncthreads();

            f16x8 Ah0 = *(const f16x8*)&Xh[wid * 32 + l16][q8];
            f16x8 Ah1 = *(const f16x8*)&Xh[wid * 32 + 16 + l16][q8];
            f16x8 Al0 = *(const f16x8*)&Xl[wid * 32 + l16][q8];
            f16x8 Al1 = *(const f16x8*)&Xl[wid * 32 + 16 + l16][q8];
#pragma unroll
            for (int fj = 0; fj < 8; ++fj) {
                f16x8 Bh = *(const f16x8*)&Sh[fj * 16 + l16][q8];
                f16x8 Bl = *(const f16x8*)&Sl[fj * 16 + l16][q8];
                acc[0][fj] = __builtin_amdgcn_mfma_f32_16x16x32_f16(Ah0, Bh, acc[0][fj], 0, 0, 0);
                acc[0][fj] = __builtin_amdgcn_mfma_f32_16x16x32_f16(Ah0, Bl, acc[0][fj], 0, 0, 0);
                acc[0][fj] = __builtin_amdgcn_mfma_f32_16x16x32_f16(Al0, Bh, acc[0][fj], 0, 0, 0);
                acc[1][fj] = __builtin_amdgcn_mfma_f32_16x16x32_f16(Ah1, Bh, acc[1][fj], 0, 0, 0);
                acc[1][fj] = __builtin_amdgcn_mfma_f32_16x16x32_f16(Ah1, Bl, acc[1][fj], 0, 0, 0);
                acc[1][fj] = __builtin_amdgcn_mfma_f32_16x16x32_f16(Al1, Bh, acc[1][fj], 0, 0, 0);
            }
        }

        // per-tile epilogue: fold 8 cols/slot into running per-lane top-2
        float s2v[8];
#pragma unroll
        for (int fj = 0; fj < 8; ++fj) s2v[fj] = s2g[n0 + fj * 16 + l16];
#pragma unroll
        for (int fi = 0; fi < 2; ++fi)
#pragma unroll
            for (int rg = 0; rg < 4; ++rg) {
                const int slot = fi * 4 + rg;
                float bv1 = v1[slot], bv2 = v2[slot]; int bi = i1[slot];
#pragma unroll
                for (int fj = 0; fj < 8; ++fj) {
                    float s = fmaf(-2.f, acc[fi][fj][rg], s2v[fj]);
                    int   n = n0 + fj * 16 + l16;
                    bool lt = (s < bv1) || (s == bv1 && n < bi);
                    bv2 = lt ? bv1 : fminf(bv2, s);
                    bi  = lt ? n : bi;
                    bv1 = lt ? s : bv1;
                }
                v1[slot] = bv1; v2[slot] = bv2; i1[slot] = bi;
            }
    }

    // merge across the 16 col-lanes of each quad group
#pragma unroll
    for (int slot = 0; slot < 8; ++slot) {
        float bv1 = v1[slot], bv2 = v2[slot]; int bi = i1[slot];
#pragma unroll
        for (int m = 1; m < 16; m <<= 1) {
            float ov1 = __shfl_xor(bv1, m);
            float ov2 = __shfl_xor(bv2, m);
            int   oi  = __shfl_xor(bi, m);
            if (ov1 < bv1 || (ov1 == bv1 && oi < bi)) {
                bv2 = fminf(bv1, ov2); bv1 = ov1; bi = oi;
            } else {
                bv2 = fminf(bv2, ov1);
            }
        }
        if (l16 == 0) {
            const int fi = slot >> 2, rg = slot & 3;
            const int row = m0 + wid * 32 + fi * 16 + quad * 4 + rg;
            pv1[(size_t)row * GY + blockIdx.y] = bv1;
            pv2[(size_t)row * GY + blockIdx.y] = bv2;
            pi1[(size_t)row * GY + blockIdx.y] = bi;
        }
    }
}

// ---------------------------------------------------------------------------
// Fast path kernel 3: merge GY chunk-top2s; write one-hot; flag + append
// uncertified queries to the fallback list.
// ---------------------------------------------------------------------------
__global__ __launch_bounds__(128) void finalize2(
    const float* __restrict__ pv1, const float* __restrict__ pv2,
    const int* __restrict__ pi1, const int* __restrict__ labels,
    const int* __restrict__ ncp, int* __restrict__ out,
    int* __restrict__ fb_cnt, int* __restrict__ fb_list) {
    const int q = blockIdx.x, tid = threadIdx.x;
    __shared__ int s_label;
    if (tid < 64) {
        float bv1 = 3.4e38f, bv2 = 3.4e38f; int bi = 0x7fffffff;
        if (tid < GY) {
            bv1 = pv1[(size_t)q * GY + tid];
            bv2 = pv2[(size_t)q * GY + tid];
            bi  = pi1[(size_t)q * GY + tid];
        }
#pragma unroll
        for (int m = 1; m < 64; m <<= 1) {
            float ov1 = __shfl_xor(bv1, m);
            float ov2 = __shfl_xor(bv2, m);
            int   oi  = __shfl_xor(bi, m);
            if (ov1 < bv1 || (ov1 == bv1 && oi < bi)) {
                bv2 = fminf(bv1, ov2); bv1 = ov1; bi = oi;
            } else {
                bv2 = fminf(bv2, ov1);
            }
        }
        if (tid == 0) {
            if (bv2 - bv1 <= EPS) {
                int slot = atomicAdd(fb_cnt, 1);
                fb_list[slot] = q;
            }
            bool is64 = true;
            for (int i = 1; i < 128; i += 2)
                if (labels[i] != 0) { is64 = false; break; }
            s_label = is64 ? labels[2 * bi] : labels[bi];
        }
    }
    __syncthreads();
    const int nc = ncp[0], lbl = s_label;
    for (int c = tid; c < nc; c += 128)
        out[q * nc + c] = (c == lbl) ? 1 : 0;
}

// ---------------------------------------------------------------------------
// Fast path kernel 4: exact fp32 rescan for listed queries, coalesced.
// 1 wave = 1 support row (64 lanes x float4 = whole 1 KB row).
// ---------------------------------------------------------------------------
__global__ __launch_bounds__(256) void fallback_scan(
    const float* __restrict__ x, const float* __restrict__ sup,
    const float* __restrict__ s2, const int* __restrict__ fb_cnt,
    const int* __restrict__ fb_list,
    float* __restrict__ fb_v, int* __restrict__ fb_i) {
    const int nslots = *fb_cnt;
    const int chunk = blockIdx.x;
    const int tid = threadIdx.x, lane = tid & 63, w = tid >> 6;
    __shared__ float wv[4];
    __shared__ int   wi[4];
    for (int slot = blockIdx.y; slot < nslots; slot += gridDim.y) {
        const int q = fb_list[slot];
        const float4 xv = ((const float4*)(x + (size_t)q * DIM))[lane];
        float best = 3.4e38f; int bi = 0x7fffffff;
        const int base = chunk * 1024 + w * 256;
        for (int r = 0; r < 256; ++r) {
            const int n = base + r;
            float4 sv = ((const float4*)(sup + (size_t)n * DIM))[lane];
            float d = fmaf(sv.x, xv.x,
                      fmaf(sv.y, xv.y,
                      fmaf(sv.z, xv.z, sv.w * xv.w)));
#pragma unroll
            for (int m = 32; m > 0; m >>= 1) d += __shfl_xor(d, m);
            float s = s2[n] - 2.f * d;
            if (s < best) { best = s; bi = n; }   // ascending n, strict <
        }
        if (lane == 0) { wv[w] = best; wi[w] = bi; }
        __syncthreads();
        if (tid == 0) {
            float bv = wv[0]; int bx = wi[0];
#pragma unroll
            for (int t = 1; t < 4; ++t)
                if (wv[t] < bv || (wv[t] == bv && wi[t] < bx)) { bv = wv[t]; bx = wi[t]; }
            fb_v[q * FBCH + chunk] = bv;
            fb_i[q * FBCH + chunk] = bx;
        }
        __syncthreads();
    }
}

// ---------------------------------------------------------------------------
// Fast path kernel 5: merge FBCH partials for listed queries, rewrite one-hot.
// ---------------------------------------------------------------------------
__global__ __launch_bounds__(64) void fallback_merge(
    const int* __restrict__ fb_cnt, const int* __restrict__ fb_list,
    const float* __restrict__ fb_v, const int* __restrict__ fb_i,
    const int* __restrict__ labels, const int* __restrict__ ncp,
    int* __restrict__ out) {
    const int nslots = *fb_cnt;
    const int lane = threadIdx.x;
    for (int slot = blockIdx.x; slot < nslots; slot += gridDim.x) {
        const int q = fb_list[slot];
        float v = 3.4e38f; int ix = 0x7fffffff;
        if (lane < FBCH) { v = fb_v[q * FBCH + lane]; ix = fb_i[q * FBCH + lane]; }
#pragma unroll
        for (int m = 1; m < 64; m <<= 1) {
            float ov = __shfl_xor(v, m);
            int   oi = __shfl_xor(ix, m);
            if (ov < v || (ov == v && oi < ix)) { v = ov; ix = oi; }
        }
        bool is64 = true;
        for (int i = 1; i < 128; i += 2)
            if (labels[i] != 0) { is64 = false; break; }
        const int lbl = is64 ? labels[2 * ix] : labels[ix];
        const int nc = ncp[0];
        for (int c = lane; c < nc; c += 64)
            out[q * nc + c] = (c == lbl) ? 1 : 0;
    }
}

// ===========================================================================
// Slow path (ws too small): proven R3 fp32 kernels.
// ===========================================================================
#define SBM 128
#define SBN 128
#define SBK 16
#define SNT 4
#define SGY (NS / (SBN * SNT))
#define SLDT (SBM + 4)

__global__ __launch_bounds__(256) void s2_kernel(const float* __restrict__ s,
                                                 float* __restrict__ s2) {
    int wave = threadIdx.x >> 6, lane = threadIdx.x & 63;
    int row = blockIdx.x * 4 + wave;
    const float4* p = (const float4*)(s + (size_t)row * DIM);
    float4 v = p[lane];
    float sum = v.x * v.x + v.y * v.y + v.z * v.z + v.w * v.w;
#pragma unroll
    for (int off = 32; off > 0; off >>= 1) sum += __shfl_xor(sum, off);
    if (lane == 0) s2[row] = sum;
}

__global__ __launch_bounds__(256) void knn_f32(const float* __restrict__ x,
                                               const float* __restrict__ sup,
                                               const float* __restrict__ s2g,
                                               float* __restrict__ pvals,
                                               int* __restrict__ pidx) {
    __shared__ float Xs[SBK][SLDT];
    __shared__ float Bs[SBK][SLDT];
    const int tid = threadIdx.x;
    const int tx = tid & 15, ty = tid >> 4;
    const int m0 = blockIdx.x * SBM, by = blockIdx.y;
    const int srow = tid >> 2, skq = (tid & 3) * 4;
    float rmin[8]; int ridx[8];
#pragma unroll
    for (int i = 0; i < 8; ++i) { rmin[i] = 3.4e38f; ridx[i] = 0x7fffffff; }
    const float* xr0 = x + (size_t)(m0 + srow) * DIM + skq;
    const float* xr1 = x + (size_t)(m0 + 64 + srow) * DIM + skq;
    for (int nt = 0; nt < SNT; ++nt) {
        const int n0 = (by * SNT + nt) * SBN;
        const float* sr0 = sup + (size_t)(n0 + srow) * DIM + skq;
        const float* sr1 = sup + (size_t)(n0 + 64 + srow) * DIM + skq;
        float acc[8][8];
#pragma unroll
        for (int i = 0; i < 8; ++i)
#pragma unroll
            for (int j = 0; j < 8; ++j) acc[i][j] = 0.0f;
        for (int kt = 0; kt < DIM / SBK; ++kt) {
            const int k0 = kt * SBK;
            float4 xv0 = *(const float4*)(xr0 + k0);
            float4 xv1 = *(const float4*)(xr1 + k0);
            float4 sv0 = *(const float4*)(sr0 + k0);
            float4 sv1 = *(const float4*)(sr1 + k0);
            __syncthreads();
            Xs[skq + 0][srow] = xv0.x; Xs[skq + 1][srow] = xv0.y;
            Xs[skq + 2][srow] = xv0.z; Xs[skq + 3][srow] = xv0.w;
            Xs[skq + 0][64 + srow] = xv1.x; Xs[skq + 1][64 + srow] = xv1.y;
            Xs[skq + 2][64 + srow] = xv1.z; Xs[skq + 3][64 + srow] = xv1.w;
            Bs[skq + 0][srow] = sv0.x; Bs[skq + 1][srow] = sv0.y;
            Bs[skq + 2][srow] = sv0.z; Bs[skq + 3][srow] = sv0.w;
            Bs[skq + 0][64 + srow] = sv1.x; Bs[skq + 1][64 + srow] = sv1.y;
            Bs[skq + 2][64 + srow] = sv1.z; Bs[skq + 3][64 + srow] = sv1.w;
            __syncthreads();
#pragma unroll
            for (int k = 0; k < SBK; ++k) {
                float4 a0 = *(const float4*)&Xs[k][ty * 4];
                float4 a1 = *(const float4*)&Xs[k][64 + ty * 4];
                float4 b0 = *(const float4*)&Bs[k][tx * 4];
                float4 b1 = *(const float4*)&Bs[k][64 + tx * 4];
                float a[8] = {a0.x, a0.y, a0.z, a0.w, a1.x, a1.y, a1.z, a1.w};
                float b[8] = {b0.x, b0.y, b0.z, b0.w, b1.x, b1.y, b1.z, b1.w};
#pragma unroll
                for (int i = 0; i < 8; ++i)
#pragma unroll
                    for (int j = 0; j < 8; ++j)
                        acc[i][j] = fmaf(a[i], b[j], acc[i][j]);
            }
        }
        const int nb0 = n0 + tx * 4, nb1 = n0 + 64 + tx * 4;
        float4 s20 = *(const float4*)(s2g + nb0);
        float4 s21 = *(const float4*)(s2g + nb1);
        float s2a[8] = {s20.x, s20.y, s20.z, s20.w, s21.x, s21.y, s21.z, s21.w};
        int nca[8] = {nb0, nb0 + 1, nb0 + 2, nb0 + 3, nb1, nb1 + 1, nb1 + 2, nb1 + 3};
#pragma unroll
        for (int i = 0; i < 8; ++i)
#pragma unroll
            for (int j = 0; j < 8; ++j) {
                float sc = fmaf(-2.0f, acc[i][j], s2a[j]);
                if (sc < rmin[i] || (sc == rmin[i] && nca[j] < ridx[i])) {
                    rmin[i] = sc; ridx[i] = nca[j];
                }
            }
    }
    __syncthreads();
    float* redv = (float*)Xs;
    int* redi = (int*)Bs;
#pragma unroll
    for (int i = 0; i < 8; ++i) {
        int mrow = (i < 4) ? (ty * 4 + i) : (64 + ty * 4 + (i - 4));
        redv[mrow * 16 + tx] = rmin[i];
        redi[mrow * 16 + tx] = ridx[i];
    }
    __syncthreads();
    if (tid < SBM) {
        float best = redv[tid * 16];
        int bi = redi[tid * 16];
#pragma unroll
        for (int t = 1; t < 16; ++t) {
            float v = redv[tid * 16 + t];
            int ix = redi[tid * 16 + t];
            if (v < best || (v == best && ix < bi)) { best = v; bi = ix; }
        }
        pvals[(size_t)(m0 + tid) * SGY + by] = best;
        pidx[(size_t)(m0 + tid) * SGY + by] = bi;
    }
}

__global__ __launch_bounds__(64) void finalize_f32(const float* __restrict__ pvals,
                                                   const int* __restrict__ pidx,
                                                   const int* __restrict__ labels,
                                                   const int* __restrict__ ncp,
                                                   int* __restrict__ out) {
    const int b = blockIdx.x, lane = threadIdx.x;
    float v = pvals[(size_t)b * SGY + lane];
    int ix = pidx[(size_t)b * SGY + lane];
#pragma unroll
    for (int off = 32; off > 0; off >>= 1) {
        float ov = __shfl_xor(v, off);
        int oi = __shfl_xor(ix, off);
        if (ov < v || (ov == v && oi < ix)) { v = ov; ix = oi; }
    }
    bool is64 = true;
    for (int i = 1; i < 128; i += 2)
        if (labels[i] != 0) { is64 = false; break; }
    const int lbl = is64 ? labels[2 * ix] : labels[ix];
    const int nc = ncp[0];
    for (int c = lane; c < nc; c += 64)
        out[b * nc + c] = (c == lbl) ? 1 : 0;
}

// ---------------------------------------------------------------------------
extern "C" void kernel_launch(void* const* d_in, const int* in_sizes, int n_in,
                              void* d_out, int out_size, void* d_ws, size_t ws_size,
                              hipStream_t stream) {
    const float* x      = (const float*)d_in[0];
    const float* sup    = (const float*)d_in[1];
    const int*   labels = (const int*)d_in[2];
    const int*   ncp    = (const int*)d_in[3];
    int* out = (int*)d_out;

    // fast-path workspace layout
    char* p = (char*)d_ws;
    float* s2      = (float*)p;           p += (size_t)NS * 4;
    float* pv1     = (float*)p;           p += (size_t)BQ * GY * 4;
    float* pv2     = (float*)p;           p += (size_t)BQ * GY * 4;
    int*   pi1     = (int*)p;             p += (size_t)BQ * GY * 4;
    int*   fb_cnt  = (int*)p;             p += 256;   // padded
    int*   fb_list = (int*)p;             p += (size_t)BQ * 4;
    float* fb_v    = (float*)p;           p += (size_t)BQ * FBCH * 4;
    int*   fb_i    = (int*)p;             p += (size_t)BQ * FBCH * 4;
    f16*   xh      = (f16*)p;             p += (size_t)BQ * DIM * 2;
    f16*   xl      = (f16*)p;             p += (size_t)BQ * DIM * 2;
    f16*   sh      = (f16*)p;             p += (size_t)NS * DIM * 2;
    f16*   sl      = (f16*)p;             p += (size_t)NS * DIM * 2;
    const size_t need = (size_t)(p - (char*)d_ws);

    if (ws_size >= need) {
        convert_kernel<<<NROWS / 4, 256, 0, stream>>>(x, sup, xh, xl, sh, sl, s2, fb_cnt);
        dim3 grid(BQ / BM, GY);
        knn_mfma<<<grid, 256, 0, stream>>>(xh, xl, sh, sl, s2, pv1, pv2, pi1);
        finalize2<<<BQ, 128, 0, stream>>>(pv1, pv2, pi1, labels, ncp, out, fb_cnt, fb_list);
        dim3 fbgrid(FBCH, 64);
        fallback_scan<<<fbgrid, 256, 0, stream>>>(x, sup, s2, fb_cnt, fb_list, fb_v, fb_i);
        fallback_merge<<<64, 64, 0, stream>>>(fb_cnt, fb_list, fb_v, fb_i, labels, ncp, out);
    } else {
        // slow path: proven fp32 pipeline (R3)
        float* ss2   = (float*)d_ws;
        float* pvals = ss2 + NS;
        int*   pidx  = (int*)(pvals + (size_t)BQ * SGY);
        s2_kernel<<<NS / 4, 256, 0, stream>>>(sup, ss2);
        dim3 grid(BQ / SBM, SGY);
        knn_f32<<<grid, 256, 0, stream>>>(x, sup, ss2, pvals, pidx);
        finalize_f32<<<BQ, 64, 0, stream>>>(pvals, pidx, labels, ncp, out);
    }
}

// Round 7
// 288.631 us; speedup vs baseline: 1.0280x; 1.0280x over previous
//
#include <hip/hip_runtime.h>

// ---------------------------------------------------------------------------
// Problem constants
#define BQ 2048
#define NS 32768
#define DIM 256
#define NROWS (NS + BQ)

// Fast-path (MFMA) tiling
#define BM 128                 // queries per block
#define BN 128                 // supports per inner tile
#define BK 32                  // K per stage (= one 16x16x32 MFMA K)
#define NTILES 2               // support tiles per block (R7: 4->2, better tail balance)
#define CHUNK (BN * NTILES)    // 256 supports per block
#define GY (NS / CHUNK)        // 128 chunks
#define EPS 2e-3f              // certified-gap threshold (>10x split error bound)
#define FBCH 32                // fallback chunks per query (1024 rows each)

typedef _Float16 f16;
typedef _Float16 f16x4 __attribute__((ext_vector_type(4)));
typedef _Float16 f16x8 __attribute__((ext_vector_type(8)));
typedef float    f32x4 __attribute__((ext_vector_type(4)));

// ---------------------------------------------------------------------------
// global->LDS DMA, 16B per lane. LDS dest = wave-uniform base + lane*16 (m104);
// per-lane source address is free, which is where the XOR swizzle lives.
// ---------------------------------------------------------------------------
__device__ __forceinline__ void gload16(const f16* g, f16* l) {
    __builtin_amdgcn_global_load_lds(
        (const __attribute__((address_space(1))) unsigned int*)g,
        (__attribute__((address_space(3))) unsigned int*)l, 16, 0, 0);
}

// Swizzled fragment pointer: row-major 32 f16/row (64 B), cell q stored at
// position q ^ ((row>>1)&3). Conflict-free b128 reads for 8 consecutive lanes:
// bank-group = 4*(row&1) + (q ^ ((row>>1)&3)) covers all 8 groups.
__device__ __forceinline__ const f16x8* fragp(const f16* base, int row, int q) {
    return (const f16x8*)(base + row * 32 + ((q ^ ((row >> 1) & 3)) << 3));
}

// ---------------------------------------------------------------------------
// Fast path kernel 1: split fp32 -> (hi,lo) f16; s2 exact fp32. One wave/row.
// Block 0 thread 0 zeroes fb_cnt.
// ---------------------------------------------------------------------------
__global__ __launch_bounds__(256) void convert_kernel(
    const float* __restrict__ x, const float* __restrict__ sup,
    f16* __restrict__ xh, f16* __restrict__ xl,
    f16* __restrict__ sh, f16* __restrict__ sl,
    float* __restrict__ s2, int* __restrict__ fb_cnt) {
    if (blockIdx.x == 0 && threadIdx.x == 0) *fb_cnt = 0;
    const int wave = threadIdx.x >> 6, lane = threadIdx.x & 63;
    const int row = blockIdx.x * 4 + wave;
    const float* src;
    f16 *dh, *dl;
    const bool issup = row < NS;
    if (issup) {
        src = sup + (size_t)row * DIM;
        dh = sh + (size_t)row * DIM; dl = sl + (size_t)row * DIM;
    } else {
        const int q = row - NS;
        src = x + (size_t)q * DIM;
        dh = xh + (size_t)q * DIM; dl = xl + (size_t)q * DIM;
    }
    float4 v = ((const float4*)src)[lane];
    f16x4 hi, lo;
    hi[0] = (f16)v.x; lo[0] = (f16)(v.x - (float)hi[0]);
    hi[1] = (f16)v.y; lo[1] = (f16)(v.y - (float)hi[1]);
    hi[2] = (f16)v.z; lo[2] = (f16)(v.z - (float)hi[2]);
    hi[3] = (f16)v.w; lo[3] = (f16)(v.w - (float)hi[3]);
    *(f16x4*)(dh + lane * 4) = hi;
    *(f16x4*)(dl + lane * 4) = lo;
    if (issup) {
        float sum = v.x * v.x + v.y * v.y + v.z * v.z + v.w * v.w;
#pragma unroll
        for (int off = 32; off > 0; off >>= 1) sum += __shfl_xor(sum, off);
        if (lane == 0) s2[row] = sum;
    }
}

// ---------------------------------------------------------------------------
// Fast path kernel 2: fused split-f16 MFMA GEMM + certified top-2 argmin.
// R7: global_load_lds staging (wave w stages array w; no staging VGPRs, no
// ds_writes), XOR-swizzled unpadded LDS (32 KB), interleaved MFMA order.
// R6 lesson: VGPR 120 + 64 AGPR acc = 184 -> 2 waves/SIMD; this cuts VGPRs.
// ---------------------------------------------------------------------------
__global__ __launch_bounds__(256) void knn_mfma(
    const f16* __restrict__ xh, const f16* __restrict__ xl,
    const f16* __restrict__ sh, const f16* __restrict__ sl,
    const float* __restrict__ s2g,
    float* __restrict__ pv1, float* __restrict__ pv2, int* __restrict__ pi1) {
    __shared__ f16 T[4][BM][32];   // [Xh|Xl|Sh|Sl][row][k], swizzled cells, 32 KB

    const int tid  = threadIdx.x;
    const int lane = tid & 63, wid = tid >> 6;
    const int l16  = lane & 15, quad = lane >> 4;
    const int m0   = blockIdx.x * BM;
    const int c0   = blockIdx.y * CHUNK;

    // DMA source pattern: lane i covers chunk-row rl=i/4, swizzled k-cell
    const int rl   = lane >> 2;
    const int c16  = (lane & 3) ^ ((rl >> 1) & 3);
    const size_t goff = (size_t)rl * DIM + c16 * 8;   // f16 elems
    f16* lsel = &T[wid][0][0];

    float v1[8], v2[8]; int i1[8];
#pragma unroll
    for (int s = 0; s < 8; ++s) { v1[s] = 3.4e38f; v2[s] = 3.4e38f; i1[s] = 0x7fffffff; }

    for (int nt = 0; nt < NTILES; ++nt) {
        const int n0 = c0 + nt * BN;
        // wave-uniform global base for this wave's array
        const f16* gw;
        if      (wid == 0) gw = xh + (size_t)m0 * DIM;
        else if (wid == 1) gw = xl + (size_t)m0 * DIM;
        else if (wid == 2) gw = sh + (size_t)n0 * DIM;
        else               gw = sl + (size_t)n0 * DIM;

        f32x4 acc[2][8];
#pragma unroll
        for (int fi = 0; fi < 2; ++fi)
#pragma unroll
            for (int fj = 0; fj < 8; ++fj) acc[fi][fj] = (f32x4){0.f, 0.f, 0.f, 0.f};

        for (int kt = 0; kt < DIM / BK; ++kt) {
            const int k0 = kt * BK;
            __syncthreads();                 // all waves done reading prev stage
#pragma unroll
            for (int c = 0; c < 8; ++c)
                gload16(gw + (size_t)(c * 16) * DIM + k0 + goff, lsel + c * 512);
            __syncthreads();                 // vmcnt(0) drain inserted by compiler

            f16x8 Ah0 = *fragp(&T[0][0][0], wid * 32 + l16,      quad);
            f16x8 Ah1 = *fragp(&T[0][0][0], wid * 32 + 16 + l16, quad);
            f16x8 Al0 = *fragp(&T[1][0][0], wid * 32 + l16,      quad);
            f16x8 Al1 = *fragp(&T[1][0][0], wid * 32 + 16 + l16, quad);
#pragma unroll
            for (int fj = 0; fj < 8; ++fj) {
                f16x8 Bh = *fragp(&T[2][0][0], fj * 16 + l16, quad);
                f16x8 Bl = *fragp(&T[3][0][0], fj * 16 + l16, quad);
                // interleave fi to break dependent-acc MFMA chains
                acc[0][fj] = __builtin_amdgcn_mfma_f32_16x16x32_f16(Ah0, Bh, acc[0][fj], 0, 0, 0);
                acc[1][fj] = __builtin_amdgcn_mfma_f32_16x16x32_f16(Ah1, Bh, acc[1][fj], 0, 0, 0);
                acc[0][fj] = __builtin_amdgcn_mfma_f32_16x16x32_f16(Ah0, Bl, acc[0][fj], 0, 0, 0);
                acc[1][fj] = __builtin_amdgcn_mfma_f32_16x16x32_f16(Ah1, Bl, acc[1][fj], 0, 0, 0);
                acc[0][fj] = __builtin_amdgcn_mfma_f32_16x16x32_f16(Al0, Bh, acc[0][fj], 0, 0, 0);
                acc[1][fj] = __builtin_amdgcn_mfma_f32_16x16x32_f16(Al1, Bh, acc[1][fj], 0, 0, 0);
            }
        }

        // per-tile epilogue: fold 8 cols/slot into running per-lane top-2
        float s2v[8];
#pragma unroll
        for (int fj = 0; fj < 8; ++fj) s2v[fj] = s2g[n0 + fj * 16 + l16];
#pragma unroll
        for (int fi = 0; fi < 2; ++fi)
#pragma unroll
            for (int rg = 0; rg < 4; ++rg) {
                const int slot = fi * 4 + rg;
                float bv1 = v1[slot], bv2 = v2[slot]; int bi = i1[slot];
#pragma unroll
                for (int fj = 0; fj < 8; ++fj) {
                    float s = fmaf(-2.f, acc[fi][fj][rg], s2v[fj]);
                    int   n = n0 + fj * 16 + l16;
                    bool lt = (s < bv1) || (s == bv1 && n < bi);
                    bv2 = lt ? bv1 : fminf(bv2, s);
                    bi  = lt ? n : bi;
                    bv1 = lt ? s : bv1;
                }
                v1[slot] = bv1; v2[slot] = bv2; i1[slot] = bi;
            }
    }

    // merge across the 16 col-lanes of each quad group
#pragma unroll
    for (int slot = 0; slot < 8; ++slot) {
        float bv1 = v1[slot], bv2 = v2[slot]; int bi = i1[slot];
#pragma unroll
        for (int m = 1; m < 16; m <<= 1) {
            float ov1 = __shfl_xor(bv1, m);
            float ov2 = __shfl_xor(bv2, m);
            int   oi  = __shfl_xor(bi, m);
            if (ov1 < bv1 || (ov1 == bv1 && oi < bi)) {
                bv2 = fminf(bv1, ov2); bv1 = ov1; bi = oi;
            } else {
                bv2 = fminf(bv2, ov1);
            }
        }
        if (l16 == 0) {
            const int fi = slot >> 2, rg = slot & 3;
            const int row = m0 + wid * 32 + fi * 16 + quad * 4 + rg;
            pv1[(size_t)row * GY + blockIdx.y] = bv1;
            pv2[(size_t)row * GY + blockIdx.y] = bv2;
            pi1[(size_t)row * GY + blockIdx.y] = bi;
        }
    }
}

// ---------------------------------------------------------------------------
// Fast path kernel 3: merge GY chunk-top2s; write one-hot; flag + append
// uncertified queries to the fallback list. Handles GY > 64 via loop.
// ---------------------------------------------------------------------------
__global__ __launch_bounds__(128) void finalize2(
    const float* __restrict__ pv1, const float* __restrict__ pv2,
    const int* __restrict__ pi1, const int* __restrict__ labels,
    const int* __restrict__ ncp, int* __restrict__ out,
    int* __restrict__ fb_cnt, int* __restrict__ fb_list) {
    const int q = blockIdx.x, tid = threadIdx.x;
    __shared__ int s_label;
    if (tid < 64) {
        float bv1 = 3.4e38f, bv2 = 3.4e38f; int bi = 0x7fffffff;
        for (int t = tid; t < GY; t += 64) {
            float ov1 = pv1[(size_t)q * GY + t];
            float ov2 = pv2[(size_t)q * GY + t];
            int   oi  = pi1[(size_t)q * GY + t];
            if (ov1 < bv1 || (ov1 == bv1 && oi < bi)) {
                bv2 = fminf(bv1, ov2); bv1 = ov1; bi = oi;
            } else {
                bv2 = fminf(bv2, ov1);
            }
        }
#pragma unroll
        for (int m = 1; m < 64; m <<= 1) {
            float ov1 = __shfl_xor(bv1, m);
            float ov2 = __shfl_xor(bv2, m);
            int   oi  = __shfl_xor(bi, m);
            if (ov1 < bv1 || (ov1 == bv1 && oi < bi)) {
                bv2 = fminf(bv1, ov2); bv1 = ov1; bi = oi;
            } else {
                bv2 = fminf(bv2, ov1);
            }
        }
        if (tid == 0) {
            if (bv2 - bv1 <= EPS) {
                int slot = atomicAdd(fb_cnt, 1);
                fb_list[slot] = q;
            }
            bool is64 = true;
            for (int i = 1; i < 128; i += 2)
                if (labels[i] != 0) { is64 = false; break; }
            s_label = is64 ? labels[2 * bi] : labels[bi];
        }
    }
    __syncthreads();
    const int nc = ncp[0], lbl = s_label;
    for (int c = tid; c < nc; c += 128)
        out[q * nc + c] = (c == lbl) ? 1 : 0;
}

// ---------------------------------------------------------------------------
// Fast path kernel 4: exact fp32 rescan for listed queries, coalesced.
// 1 wave = 1 support row (64 lanes x float4 = whole 1 KB row).
// ---------------------------------------------------------------------------
__global__ __launch_bounds__(256) void fallback_scan(
    const float* __restrict__ x, const float* __restrict__ sup,
    const float* __restrict__ s2, const int* __restrict__ fb_cnt,
    const int* __restrict__ fb_list,
    float* __restrict__ fb_v, int* __restrict__ fb_i) {
    const int nslots = *fb_cnt;
    const int chunk = blockIdx.x;
    const int tid = threadIdx.x, lane = tid & 63, w = tid >> 6;
    __shared__ float wv[4];
    __shared__ int   wi[4];
    for (int slot = blockIdx.y; slot < nslots; slot += gridDim.y) {
        const int q = fb_list[slot];
        const float4 xv = ((const float4*)(x + (size_t)q * DIM))[lane];
        float best = 3.4e38f; int bi = 0x7fffffff;
        const int base = chunk * 1024 + w * 256;
        for (int r = 0; r < 256; ++r) {
            const int n = base + r;
            float4 sv = ((const float4*)(sup + (size_t)n * DIM))[lane];
            float d = fmaf(sv.x, xv.x,
                      fmaf(sv.y, xv.y,
                      fmaf(sv.z, xv.z, sv.w * xv.w)));
#pragma unroll
            for (int m = 32; m > 0; m >>= 1) d += __shfl_xor(d, m);
            float s = s2[n] - 2.f * d;
            if (s < best) { best = s; bi = n; }   // ascending n, strict <
        }
        if (lane == 0) { wv[w] = best; wi[w] = bi; }
        __syncthreads();
        if (tid == 0) {
            float bv = wv[0]; int bx = wi[0];
#pragma unroll
            for (int t = 1; t < 4; ++t)
                if (wv[t] < bv || (wv[t] == bv && wi[t] < bx)) { bv = wv[t]; bx = wi[t]; }
            fb_v[q * FBCH + chunk] = bv;
            fb_i[q * FBCH + chunk] = bx;
        }
        __syncthreads();
    }
}

// ---------------------------------------------------------------------------
// Fast path kernel 5: merge FBCH partials for listed queries, rewrite one-hot.
// ---------------------------------------------------------------------------
__global__ __launch_bounds__(64) void fallback_merge(
    const int* __restrict__ fb_cnt, const int* __restrict__ fb_list,
    const float* __restrict__ fb_v, const int* __restrict__ fb_i,
    const int* __restrict__ labels, const int* __restrict__ ncp,
    int* __restrict__ out) {
    const int nslots = *fb_cnt;
    const int lane = threadIdx.x;
    for (int slot = blockIdx.x; slot < nslots; slot += gridDim.x) {
        const int q = fb_list[slot];
        float v = 3.4e38f; int ix = 0x7fffffff;
        if (lane < FBCH) { v = fb_v[q * FBCH + lane]; ix = fb_i[q * FBCH + lane]; }
#pragma unroll
        for (int m = 1; m < 64; m <<= 1) {
            float ov = __shfl_xor(v, m);
            int   oi = __shfl_xor(ix, m);
            if (ov < v || (ov == v && oi < ix)) { v = ov; ix = oi; }
        }
        bool is64 = true;
        for (int i = 1; i < 128; i += 2)
            if (labels[i] != 0) { is64 = false; break; }
        const int lbl = is64 ? labels[2 * ix] : labels[ix];
        const int nc = ncp[0];
        for (int c = lane; c < nc; c += 64)
            out[q * nc + c] = (c == lbl) ? 1 : 0;
    }
}

// ===========================================================================
// Slow path (ws too small): proven R3 fp32 kernels.
// ===========================================================================
#define SBM 128
#define SBN 128
#define SBK 16
#define SNT 4
#define SGY (NS / (SBN * SNT))
#define SLDT (SBM + 4)

__global__ __launch_bounds__(256) void s2_kernel(const float* __restrict__ s,
                                                 float* __restrict__ s2) {
    int wave = threadIdx.x >> 6, lane = threadIdx.x & 63;
    int row = blockIdx.x * 4 + wave;
    const float4* p = (const float4*)(s + (size_t)row * DIM);
    float4 v = p[lane];
    float sum = v.x * v.x + v.y * v.y + v.z * v.z + v.w * v.w;
#pragma unroll
    for (int off = 32; off > 0; off >>= 1) sum += __shfl_xor(sum, off);
    if (lane == 0) s2[row] = sum;
}

__global__ __launch_bounds__(256) void knn_f32(const float* __restrict__ x,
                                               const float* __restrict__ sup,
                                               const float* __restrict__ s2g,
                                               float* __restrict__ pvals,
                                               int* __restrict__ pidx) {
    __shared__ float Xs[SBK][SLDT];
    __shared__ float Bs[SBK][SLDT];
    const int tid = threadIdx.x;
    const int tx = tid & 15, ty = tid >> 4;
    const int m0 = blockIdx.x * SBM, by = blockIdx.y;
    const int srow = tid >> 2, skq = (tid & 3) * 4;
    float rmin[8]; int ridx[8];
#pragma unroll
    for (int i = 0; i < 8; ++i) { rmin[i] = 3.4e38f; ridx[i] = 0x7fffffff; }
    const float* xr0 = x + (size_t)(m0 + srow) * DIM + skq;
    const float* xr1 = x + (size_t)(m0 + 64 + srow) * DIM + skq;
    for (int nt = 0; nt < SNT; ++nt) {
        const int n0 = (by * SNT + nt) * SBN;
        const float* sr0 = sup + (size_t)(n0 + srow) * DIM + skq;
        const float* sr1 = sup + (size_t)(n0 + 64 + srow) * DIM + skq;
        float acc[8][8];
#pragma unroll
        for (int i = 0; i < 8; ++i)
#pragma unroll
            for (int j = 0; j < 8; ++j) acc[i][j] = 0.0f;
        for (int kt = 0; kt < DIM / SBK; ++kt) {
            const int k0 = kt * SBK;
            float4 xv0 = *(const float4*)(xr0 + k0);
            float4 xv1 = *(const float4*)(xr1 + k0);
            float4 sv0 = *(const float4*)(sr0 + k0);
            float4 sv1 = *(const float4*)(sr1 + k0);
            __syncthreads();
            Xs[skq + 0][srow] = xv0.x; Xs[skq + 1][srow] = xv0.y;
            Xs[skq + 2][srow] = xv0.z; Xs[skq + 3][srow] = xv0.w;
            Xs[skq + 0][64 + srow] = xv1.x; Xs[skq + 1][64 + srow] = xv1.y;
            Xs[skq + 2][64 + srow] = xv1.z; Xs[skq + 3][64 + srow] = xv1.w;
            Bs[skq + 0][srow] = sv0.x; Bs[skq + 1][srow] = sv0.y;
            Bs[skq + 2][srow] = sv0.z; Bs[skq + 3][srow] = sv0.w;
            Bs[skq + 0][64 + srow] = sv1.x; Bs[skq + 1][64 + srow] = sv1.y;
            Bs[skq + 2][64 + srow] = sv1.z; Bs[skq + 3][64 + srow] = sv1.w;
            __syncthreads();
#pragma unroll
            for (int k = 0; k < SBK; ++k) {
                float4 a0 = *(const float4*)&Xs[k][ty * 4];
                float4 a1 = *(const float4*)&Xs[k][64 + ty * 4];
                float4 b0 = *(const float4*)&Bs[k][tx * 4];
                float4 b1 = *(const float4*)&Bs[k][64 + tx * 4];
                float a[8] = {a0.x, a0.y, a0.z, a0.w, a1.x, a1.y, a1.z, a1.w};
                float b[8] = {b0.x, b0.y, b0.z, b0.w, b1.x, b1.y, b1.z, b1.w};
#pragma unroll
                for (int i = 0; i < 8; ++i)
#pragma unroll
                    for (int j = 0; j < 8; ++j)
                        acc[i][j] = fmaf(a[i], b[j], acc[i][j]);
            }
        }
        const int nb0 = n0 + tx * 4, nb1 = n0 + 64 + tx * 4;
        float4 s20 = *(const float4*)(s2g + nb0);
        float4 s21 = *(const float4*)(s2g + nb1);
        float s2a[8] = {s20.x, s20.y, s20.z, s20.w, s21.x, s21.y, s21.z, s21.w};
        int nca[8] = {nb0, nb0 + 1, nb0 + 2, nb0 + 3, nb1, nb1 + 1, nb1 + 2, nb1 + 3};
#pragma unroll
        for (int i = 0; i < 8; ++i)
#pragma unroll
            for (int j = 0; j < 8; ++j) {
                float sc = fmaf(-2.0f, acc[i][j], s2a[j]);
                if (sc < rmin[i] || (sc == rmin[i] && nca[j] < ridx[i])) {
                    rmin[i] = sc; ridx[i] = nca[j];
                }
            }
    }
    __syncthreads();
    float* redv = (float*)Xs;
    int* redi = (int*)Bs;
#pragma unroll
    for (int i = 0; i < 8; ++i) {
        int mrow = (i < 4) ? (ty * 4 + i) : (64 + ty * 4 + (i - 4));
        redv[mrow * 16 + tx] = rmin[i];
        redi[mrow * 16 + tx] = ridx[i];
    }
    __syncthreads();
    if (tid < SBM) {
        float best = redv[tid * 16];
        int bi = redi[tid * 16];
#pragma unroll
        for (int t = 1; t < 16; ++t) {
            float v = redv[tid * 16 + t];
            int ix = redi[tid * 16 + t];
            if (v < best || (v == best && ix < bi)) { best = v; bi = ix; }
        }
        pvals[(size_t)(m0 + tid) * SGY + by] = best;
        pidx[(size_t)(m0 + tid) * SGY + by] = bi;
    }
}

__global__ __launch_bounds__(64) void finalize_f32(const float* __restrict__ pvals,
                                                   const int* __restrict__ pidx,
                                                   const int* __restrict__ labels,
                                                   const int* __restrict__ ncp,
                                                   int* __restrict__ out) {
    const int b = blockIdx.x, lane = threadIdx.x;
    float v = pvals[(size_t)b * SGY + lane];
    int ix = pidx[(size_t)b * SGY + lane];
#pragma unroll
    for (int off = 32; off > 0; off >>= 1) {
        float ov = __shfl_xor(v, off);
        int oi = __shfl_xor(ix, off);
        if (ov < v || (ov == v && oi < ix)) { v = ov; ix = oi; }
    }
    bool is64 = true;
    for (int i = 1; i < 128; i += 2)
        if (labels[i] != 0) { is64 = false; break; }
    const int lbl = is64 ? labels[2 * ix] : labels[ix];
    const int nc = ncp[0];
    for (int c = lane; c < nc; c += 64)
        out[b * nc + c] = (c == lbl) ? 1 : 0;
}

// ---------------------------------------------------------------------------
extern "C" void kernel_launch(void* const* d_in, const int* in_sizes, int n_in,
                              void* d_out, int out_size, void* d_ws, size_t ws_size,
                              hipStream_t stream) {
    const float* x      = (const float*)d_in[0];
    const float* sup    = (const float*)d_in[1];
    const int*   labels = (const int*)d_in[2];
    const int*   ncp    = (const int*)d_in[3];
    int* out = (int*)d_out;

    // fast-path workspace layout
    char* p = (char*)d_ws;
    float* s2      = (float*)p;           p += (size_t)NS * 4;
    float* pv1     = (float*)p;           p += (size_t)BQ * GY * 4;
    float* pv2     = (float*)p;           p += (size_t)BQ * GY * 4;
    int*   pi1     = (int*)p;             p += (size_t)BQ * GY * 4;
    int*   fb_cnt  = (int*)p;             p += 256;   // padded
    int*   fb_list = (int*)p;             p += (size_t)BQ * 4;
    float* fb_v    = (float*)p;           p += (size_t)BQ * FBCH * 4;
    int*   fb_i    = (int*)p;             p += (size_t)BQ * FBCH * 4;
    f16*   xh      = (f16*)p;             p += (size_t)BQ * DIM * 2;
    f16*   xl      = (f16*)p;             p += (size_t)BQ * DIM * 2;
    f16*   sh      = (f16*)p;             p += (size_t)NS * DIM * 2;
    f16*   sl      = (f16*)p;             p += (size_t)NS * DIM * 2;
    const size_t need = (size_t)(p - (char*)d_ws);

    if (ws_size >= need) {
        convert_kernel<<<NROWS / 4, 256, 0, stream>>>(x, sup, xh, xl, sh, sl, s2, fb_cnt);
        dim3 grid(BQ / BM, GY);
        knn_mfma<<<grid, 256, 0, stream>>>(xh, xl, sh, sl, s2, pv1, pv2, pi1);
        finalize2<<<BQ, 128, 0, stream>>>(pv1, pv2, pi1, labels, ncp, out, fb_cnt, fb_list);
        dim3 fbgrid(FBCH, 64);
        fallback_scan<<<fbgrid, 256, 0, stream>>>(x, sup, s2, fb_cnt, fb_list, fb_v, fb_i);
        fallback_merge<<<64, 64, 0, stream>>>(fb_cnt, fb_list, fb_v, fb_i, labels, ncp, out);
    } else {
        // slow path: proven fp32 pipeline (R3)
        float* ss2   = (float*)d_ws;
        float* pvals = ss2 + NS;
        int*   pidx  = (int*)(pvals + (size_t)BQ * SGY);
        s2_kernel<<<NS / 4, 256, 0, stream>>>(sup, ss2);
        dim3 grid(BQ / SBM, SGY);
        knn_f32<<<grid, 256, 0, stream>>>(x, sup, ss2, pvals, pidx);
        finalize_f32<<<BQ, 64, 0, stream>>>(pvals, pidx, labels, ncp, out);
    }
}

// Round 8
// 266.103 us; speedup vs baseline: 1.1151x; 1.0847x over previous
//
#include <hip/hip_runtime.h>

// ---------------------------------------------------------------------------
// Problem constants
#define BQ 2048
#define NS 32768
#define DIM 256
#define NROWS (NS + BQ)

// Fast-path (MFMA) tiling
#define BM 128                 // queries per block
#define BN 128                 // supports per inner tile
#define BK 32                  // K per stage (= one 16x16x32 MFMA K)
#define NTILES 2               // support tiles per block
#define CHUNK (BN * NTILES)    // 256 supports per block
#define GY (NS / CHUNK)        // 128 chunks
#define NSTAGE (NTILES * (DIM / BK))   // 16 pipeline stages
// Certification: score = s2 - 2*(x_hi+x_lo)\cdot s_hi; only dropped term is
// x\cdot s_lo (std ~4.5e-3 per score, max over 32k ~0.019). EPS=0.05 > worst
// err_i + max_j err_j; ties/near-ties go to the exact fp32 fallback.
#define EPS 0.05f
#define FBCH 32                // fallback chunks per query (1024 rows each)

typedef _Float16 f16;
typedef _Float16 f16x4 __attribute__((ext_vector_type(4)));
typedef _Float16 f16x8 __attribute__((ext_vector_type(8)));
typedef float    f32x4 __attribute__((ext_vector_type(4)));

// ---------------------------------------------------------------------------
// global->LDS DMA, 16B per lane. LDS dest = wave-uniform base + lane*16;
// per-lane source address carries the XOR swizzle.
// ---------------------------------------------------------------------------
__device__ __forceinline__ void gload16(const f16* g, f16* l) {
    __builtin_amdgcn_global_load_lds(
        (const __attribute__((address_space(1))) unsigned int*)g,
        (__attribute__((address_space(3))) unsigned int*)l, 16, 0, 0);
}

// Swizzled fragment pointer: row-major 32 f16/row (64 B), cell q stored at
// q ^ ((row>>1)&3). Conflict-free b128 reads (R7-verified: SQ_LDS_BANK_CONFLICT=0).
__device__ __forceinline__ const f16x8* fragp(const f16* base, int row, int q) {
    return (const f16x8*)(base + row * 32 + ((q ^ ((row >> 1) & 3)) << 3));
}

// ---------------------------------------------------------------------------
// Fast path kernel 1: split fp32 x -> (hi,lo) f16, support -> hi f16 only;
// s2 exact fp32. One wave per row. Block 0 thread 0 zeroes fb_cnt.
// ---------------------------------------------------------------------------
__global__ __launch_bounds__(256) void convert_kernel(
    const float* __restrict__ x, const float* __restrict__ sup,
    f16* __restrict__ xh, f16* __restrict__ xl, f16* __restrict__ sh,
    float* __restrict__ s2, int* __restrict__ fb_cnt) {
    if (blockIdx.x == 0 && threadIdx.x == 0) *fb_cnt = 0;
    const int wave = threadIdx.x >> 6, lane = threadIdx.x & 63;
    const int row = blockIdx.x * 4 + wave;
    if (row < NS) {
        const float* src = sup + (size_t)row * DIM;
        float4 v = ((const float4*)src)[lane];
        f16x4 hi;
        hi[0] = (f16)v.x; hi[1] = (f16)v.y; hi[2] = (f16)v.z; hi[3] = (f16)v.w;
        *(f16x4*)(sh + (size_t)row * DIM + lane * 4) = hi;
        float sum = v.x * v.x + v.y * v.y + v.z * v.z + v.w * v.w;
#pragma unroll
        for (int off = 32; off > 0; off >>= 1) sum += __shfl_xor(sum, off);
        if (lane == 0) s2[row] = sum;
    } else {
        const int q = row - NS;
        float4 v = ((const float4*)(x + (size_t)q * DIM))[lane];
        f16x4 hi, lo;
        hi[0] = (f16)v.x; lo[0] = (f16)(v.x - (float)hi[0]);
        hi[1] = (f16)v.y; lo[1] = (f16)(v.y - (float)hi[1]);
        hi[2] = (f16)v.z; lo[2] = (f16)(v.z - (float)hi[2]);
        hi[3] = (f16)v.w; lo[3] = (f16)(v.w - (float)hi[3]);
        *(f16x4*)(xh + (size_t)q * DIM + lane * 4) = hi;
        *(f16x4*)(xl + (size_t)q * DIM + lane * 4) = lo;
    }
}

// ---------------------------------------------------------------------------
// Fast path kernel 2: fused 2-term split-f16 MFMA GEMM + certified top-2.
// R8: 3 staged arrays (Xh,Xl,Sh), single-barrier double-buffered pipeline
// (DMA for stage s+1 issued post-barrier, consumed next iteration; race-free
// because issue is after the barrier that ends all reads of that buffer),
// tie-break-free min/max top-2 epilogue (ties -> gap 0 -> exact fallback).
// ---------------------------------------------------------------------------
__global__ __launch_bounds__(256) void knn_mfma(
    const f16* __restrict__ xh, const f16* __restrict__ xl,
    const f16* __restrict__ sh, const float* __restrict__ s2g,
    float* __restrict__ pv1, float* __restrict__ pv2, int* __restrict__ pi1) {
    __shared__ f16 T[2][3][BM][32];   // 48 KB: [buf][Xh|Xl|Sh][row][swizzled k]

    const int tid  = threadIdx.x;
    const int lane = tid & 63, wid = tid >> 6;
    const int l16  = lane & 15, quad = lane >> 4;
    const int m0   = blockIdx.x * BM;
    const int c0   = blockIdx.y * CHUNK;

    // DMA source pattern: lane covers 16 B = 8 f16 = one swizzled cell.
    // row-within-call = lane>>2; swizzle phase depends only on lane (16|row0).
    const int rl = lane >> 2;
    const int qs = (lane & 3) ^ ((rl >> 1) & 3);
    const size_t srcoff = (size_t)rl * DIM + qs * 8;

    // wave staging roles: w0 -> Xh (8 calls), w1 -> Xl (8), w2 -> Sh rows
    // 0..63 (4), w3 -> Sh rows 64..127 (4). All wave-uniform bases.
    const f16* xbase = (wid == 0) ? xh : xl;

    float v1[8], v2[8]; int i1[8];
#pragma unroll
    for (int s = 0; s < 8; ++s) { v1[s] = 3.4e38f; v2[s] = 3.4e38f; i1[s] = 0; }

    // stage(s): issue DMA for pipeline stage s into buffer s&1
    auto stage = [&](int s) {
        const int b  = s & 1;
        const int k0 = (s & 7) * BK;
        const int n0 = c0 + (s >> 3) * BN;
        if (wid < 2) {
            const f16* g = xbase + (size_t)m0 * DIM + k0;
            f16* l = &T[b][wid][0][0];
#pragma unroll
            for (int c = 0; c < 8; ++c)
                gload16(g + (size_t)(c * 16) * DIM + srcoff, l + c * 512);
        } else {
            const int r0 = (wid - 2) * 64;
            const f16* g = sh + (size_t)(n0 + r0) * DIM + k0;
            f16* l = &T[b][2][r0][0];
#pragma unroll
            for (int c = 0; c < 4; ++c)
                gload16(g + (size_t)(c * 16) * DIM + srcoff, l + c * 512);
        }
    };

    stage(0);   // prologue prefetch

    for (int nt = 0; nt < NTILES; ++nt) {
        const int n0 = c0 + nt * BN;
        f32x4 acc[2][8];
#pragma unroll
        for (int fi = 0; fi < 2; ++fi)
#pragma unroll
            for (int fj = 0; fj < 8; ++fj) acc[fi][fj] = (f32x4){0.f, 0.f, 0.f, 0.f};

        for (int kt = 0; kt < DIM / BK; ++kt) {
            const int s = nt * (DIM / BK) + kt;
            __syncthreads();              // drains DMA for stage s (issued last iter)
            if (s + 1 < NSTAGE) stage(s + 1);
            const f16* Tb = &T[s & 1][0][0][0];

            f16x8 Ah0 = *fragp(Tb,            wid * 32 + l16,      quad);
            f16x8 Ah1 = *fragp(Tb,            wid * 32 + 16 + l16, quad);
            f16x8 Al0 = *fragp(Tb + BM * 32,  wid * 32 + l16,      quad);
            f16x8 Al1 = *fragp(Tb + BM * 32,  wid * 32 + 16 + l16, quad);
#pragma unroll
            for (int fj = 0; fj < 8; ++fj) {
                f16x8 Bh = *fragp(Tb + 2 * BM * 32, fj * 16 + l16, quad);
                acc[0][fj] = __builtin_amdgcn_mfma_f32_16x16x32_f16(Ah0, Bh, acc[0][fj], 0, 0, 0);
                acc[1][fj] = __builtin_amdgcn_mfma_f32_16x16x32_f16(Ah1, Bh, acc[1][fj], 0, 0, 0);
                acc[0][fj] = __builtin_amdgcn_mfma_f32_16x16x32_f16(Al0, Bh, acc[0][fj], 0, 0, 0);
                acc[1][fj] = __builtin_amdgcn_mfma_f32_16x16x32_f16(Al1, Bh, acc[1][fj], 0, 0, 0);
            }
        }

        // per-tile epilogue: tie-break-free running top-2 (values) + argmin idx
        float s2v[8];
#pragma unroll
        for (int fj = 0; fj < 8; ++fj) s2v[fj] = s2g[n0 + fj * 16 + l16];
#pragma unroll
        for (int fi = 0; fi < 2; ++fi)
#pragma unroll
            for (int rg = 0; rg < 4; ++rg) {
                const int slot = fi * 4 + rg;
                float bv1 = v1[slot], bv2 = v2[slot]; int bi = i1[slot];
#pragma unroll
                for (int fj = 0; fj < 8; ++fj) {
                    float s = fmaf(-2.f, acc[fi][fj][rg], s2v[fj]);
                    bv2 = fminf(bv2, fmaxf(bv1, s));
                    bi  = (s < bv1) ? (n0 + fj * 16 + l16) : bi;
                    bv1 = fminf(bv1, s);
                }
                v1[slot] = bv1; v2[slot] = bv2; i1[slot] = bi;
            }
    }

    // merge across the 16 col-lanes of each quad group (value-only top-2)
#pragma unroll
    for (int slot = 0; slot < 8; ++slot) {
        float bv1 = v1[slot], bv2 = v2[slot]; int bi = i1[slot];
#pragma unroll
        for (int m = 1; m < 16; m <<= 1) {
            float ov1 = __shfl_xor(bv1, m);
            float ov2 = __shfl_xor(bv2, m);
            int   oi  = __shfl_xor(bi, m);
            float nb2 = fminf(fminf(bv2, ov2), fmaxf(bv1, ov1));
            bi  = (ov1 < bv1) ? oi : bi;
            bv1 = fminf(bv1, ov1);
            bv2 = nb2;
        }
        if (l16 == 0) {
            const int fi = slot >> 2, rg = slot & 3;
            const int row = m0 + wid * 32 + fi * 16 + quad * 4 + rg;
            pv1[(size_t)row * GY + blockIdx.y] = bv1;
            pv2[(size_t)row * GY + blockIdx.y] = bv2;
            pi1[(size_t)row * GY + blockIdx.y] = bi;
        }
    }
}

// ---------------------------------------------------------------------------
// Fast path kernel 3: merge GY chunk-top2s; one-hot; flag uncertified queries.
// ---------------------------------------------------------------------------
__global__ __launch_bounds__(128) void finalize2(
    const float* __restrict__ pv1, const float* __restrict__ pv2,
    const int* __restrict__ pi1, const int* __restrict__ labels,
    const int* __restrict__ ncp, int* __restrict__ out,
    int* __restrict__ fb_cnt, int* __restrict__ fb_list) {
    const int q = blockIdx.x, tid = threadIdx.x;
    __shared__ int s_label;
    if (tid < 64) {
        float bv1 = 3.4e38f, bv2 = 3.4e38f; int bi = 0;
        for (int t = tid; t < GY; t += 64) {
            float ov1 = pv1[(size_t)q * GY + t];
            float ov2 = pv2[(size_t)q * GY + t];
            int   oi  = pi1[(size_t)q * GY + t];
            float nb2 = fminf(fminf(bv2, ov2), fmaxf(bv1, ov1));
            bi  = (ov1 < bv1) ? oi : bi;
            bv1 = fminf(bv1, ov1);
            bv2 = nb2;
        }
#pragma unroll
        for (int m = 1; m < 64; m <<= 1) {
            float ov1 = __shfl_xor(bv1, m);
            float ov2 = __shfl_xor(bv2, m);
            int   oi  = __shfl_xor(bi, m);
            float nb2 = fminf(fminf(bv2, ov2), fmaxf(bv1, ov1));
            bi  = (ov1 < bv1) ? oi : bi;
            bv1 = fminf(bv1, ov1);
            bv2 = nb2;
        }
        if (tid == 0) {
            if (bv2 - bv1 <= EPS) {
                int slot = atomicAdd(fb_cnt, 1);
                fb_list[slot] = q;
            }
            bool is64 = true;
            for (int i = 1; i < 128; i += 2)
                if (labels[i] != 0) { is64 = false; break; }
            s_label = is64 ? labels[2 * bi] : labels[bi];
        }
    }
    __syncthreads();
    const int nc = ncp[0], lbl = s_label;
    for (int c = tid; c < nc; c += 128)
        out[q * nc + c] = (c == lbl) ? 1 : 0;
}

// ---------------------------------------------------------------------------
// Fast path kernel 4: exact fp32 rescan for listed queries, coalesced.
// 1 wave = 1 support row (64 lanes x float4 = whole 1 KB row).
// ---------------------------------------------------------------------------
__global__ __launch_bounds__(256) void fallback_scan(
    const float* __restrict__ x, const float* __restrict__ sup,
    const float* __restrict__ s2, const int* __restrict__ fb_cnt,
    const int* __restrict__ fb_list,
    float* __restrict__ fb_v, int* __restrict__ fb_i) {
    const int nslots = *fb_cnt;
    const int chunk = blockIdx.x;
    const int tid = threadIdx.x, lane = tid & 63, w = tid >> 6;
    __shared__ float wv[4];
    __shared__ int   wi[4];
    for (int slot = blockIdx.y; slot < nslots; slot += gridDim.y) {
        const int q = fb_list[slot];
        const float4 xv = ((const float4*)(x + (size_t)q * DIM))[lane];
        float best = 3.4e38f; int bi = 0x7fffffff;
        const int base = chunk * 1024 + w * 256;
        for (int r = 0; r < 256; ++r) {
            const int n = base + r;
            float4 sv = ((const float4*)(sup + (size_t)n * DIM))[lane];
            float d = fmaf(sv.x, xv.x,
                      fmaf(sv.y, xv.y,
                      fmaf(sv.z, xv.z, sv.w * xv.w)));
#pragma unroll
            for (int m = 32; m > 0; m >>= 1) d += __shfl_xor(d, m);
            float s = s2[n] - 2.f * d;
            if (s < best) { best = s; bi = n; }   // ascending n, strict <
        }
        if (lane == 0) { wv[w] = best; wi[w] = bi; }
        __syncthreads();
        if (tid == 0) {
            float bv = wv[0]; int bx = wi[0];
#pragma unroll
            for (int t = 1; t < 4; ++t)
                if (wv[t] < bv || (wv[t] == bv && wi[t] < bx)) { bv = wv[t]; bx = wi[t]; }
            fb_v[q * FBCH + chunk] = bv;
            fb_i[q * FBCH + chunk] = bx;
        }
        __syncthreads();
    }
}

// ---------------------------------------------------------------------------
// Fast path kernel 5: merge FBCH partials for listed queries, rewrite one-hot.
// ---------------------------------------------------------------------------
__global__ __launch_bounds__(64) void fallback_merge(
    const int* __restrict__ fb_cnt, const int* __restrict__ fb_list,
    const float* __restrict__ fb_v, const int* __restrict__ fb_i,
    const int* __restrict__ labels, const int* __restrict__ ncp,
    int* __restrict__ out) {
    const int nslots = *fb_cnt;
    const int lane = threadIdx.x;
    for (int slot = blockIdx.x; slot < nslots; slot += gridDim.x) {
        const int q = fb_list[slot];
        float v = 3.4e38f; int ix = 0x7fffffff;
        if (lane < FBCH) { v = fb_v[q * FBCH + lane]; ix = fb_i[q * FBCH + lane]; }
#pragma unroll
        for (int m = 1; m < 64; m <<= 1) {
            float ov = __shfl_xor(v, m);
            int   oi = __shfl_xor(ix, m);
            if (ov < v || (ov == v && oi < ix)) { v = ov; ix = oi; }
        }
        bool is64 = true;
        for (int i = 1; i < 128; i += 2)
            if (labels[i] != 0) { is64 = false; break; }
        const int lbl = is64 ? labels[2 * ix] : labels[ix];
        const int nc = ncp[0];
        for (int c = lane; c < nc; c += 64)
            out[q * nc + c] = (c == lbl) ? 1 : 0;
    }
}

// ===========================================================================
// Slow path (ws too small): proven R3 fp32 kernels.
// ===========================================================================
#define SBM 128
#define SBN 128
#define SBK 16
#define SNT 4
#define SGY (NS / (SBN * SNT))
#define SLDT (SBM + 4)

__global__ __launch_bounds__(256) void s2_kernel(const float* __restrict__ s,
                                                 float* __restrict__ s2) {
    int wave = threadIdx.x >> 6, lane = threadIdx.x & 63;
    int row = blockIdx.x * 4 + wave;
    const float4* p = (const float4*)(s + (size_t)row * DIM);
    float4 v = p[lane];
    float sum = v.x * v.x + v.y * v.y + v.z * v.z + v.w * v.w;
#pragma unroll
    for (int off = 32; off > 0; off >>= 1) sum += __shfl_xor(sum, off);
    if (lane == 0) s2[row] = sum;
}

__global__ __launch_bounds__(256) void knn_f32(const float* __restrict__ x,
                                               const float* __restrict__ sup,
                                               const float* __restrict__ s2g,
                                               float* __restrict__ pvals,
                                               int* __restrict__ pidx) {
    __shared__ float Xs[SBK][SLDT];
    __shared__ float Bs[SBK][SLDT];
    const int tid = threadIdx.x;
    const int tx = tid & 15, ty = tid >> 4;
    const int m0 = blockIdx.x * SBM, by = blockIdx.y;
    const int srow = tid >> 2, skq = (tid & 3) * 4;
    float rmin[8]; int ridx[8];
#pragma unroll
    for (int i = 0; i < 8; ++i) { rmin[i] = 3.4e38f; ridx[i] = 0x7fffffff; }
    const float* xr0 = x + (size_t)(m0 + srow) * DIM + skq;
    const float* xr1 = x + (size_t)(m0 + 64 + srow) * DIM + skq;
    for (int nt = 0; nt < SNT; ++nt) {
        const int n0 = (by * SNT + nt) * SBN;
        const float* sr0 = sup + (size_t)(n0 + srow) * DIM + skq;
        const float* sr1 = sup + (size_t)(n0 + 64 + srow) * DIM + skq;
        float acc[8][8];
#pragma unroll
        for (int i = 0; i < 8; ++i)
#pragma unroll
            for (int j = 0; j < 8; ++j) acc[i][j] = 0.0f;
        for (int kt = 0; kt < DIM / SBK; ++kt) {
            const int k0 = kt * SBK;
            float4 xv0 = *(const float4*)(xr0 + k0);
            float4 xv1 = *(const float4*)(xr1 + k0);
            float4 sv0 = *(const float4*)(sr0 + k0);
            float4 sv1 = *(const float4*)(sr1 + k0);
            __syncthreads();
            Xs[skq + 0][srow] = xv0.x; Xs[skq + 1][srow] = xv0.y;
            Xs[skq + 2][srow] = xv0.z; Xs[skq + 3][srow] = xv0.w;
            Xs[skq + 0][64 + srow] = xv1.x; Xs[skq + 1][64 + srow] = xv1.y;
            Xs[skq + 2][64 + srow] = xv1.z; Xs[skq + 3][64 + srow] = xv1.w;
            Bs[skq + 0][srow] = sv0.x; Bs[skq + 1][srow] = sv0.y;
            Bs[skq + 2][srow] = sv0.z; Bs[skq + 3][srow] = sv0.w;
            Bs[skq + 0][64 + srow] = sv1.x; Bs[skq + 1][64 + srow] = sv1.y;
            Bs[skq + 2][64 + srow] = sv1.z; Bs[skq + 3][64 + srow] = sv1.w;
            __syncthreads();
#pragma unroll
            for (int k = 0; k < SBK; ++k) {
                float4 a0 = *(const float4*)&Xs[k][ty * 4];
                float4 a1 = *(const float4*)&Xs[k][64 + ty * 4];
                float4 b0 = *(const float4*)&Bs[k][tx * 4];
                float4 b1 = *(const float4*)&Bs[k][64 + tx * 4];
                float a[8] = {a0.x, a0.y, a0.z, a0.w, a1.x, a1.y, a1.z, a1.w};
                float b[8] = {b0.x, b0.y, b0.z, b0.w, b1.x, b1.y, b1.z, b1.w};
#pragma unroll
                for (int i = 0; i < 8; ++i)
#pragma unroll
                    for (int j = 0; j < 8; ++j)
                        acc[i][j] = fmaf(a[i], b[j], acc[i][j]);
            }
        }
        const int nb0 = n0 + tx * 4, nb1 = n0 + 64 + tx * 4;
        float4 s20 = *(const float4*)(s2g + nb0);
        float4 s21 = *(const float4*)(s2g + nb1);
        float s2a[8] = {s20.x, s20.y, s20.z, s20.w, s21.x, s21.y, s21.z, s21.w};
        int nca[8] = {nb0, nb0 + 1, nb0 + 2, nb0 + 3, nb1, nb1 + 1, nb1 + 2, nb1 + 3};
#pragma unroll
        for (int i = 0; i < 8; ++i)
#pragma unroll
            for (int j = 0; j < 8; ++j) {
                float sc = fmaf(-2.0f, acc[i][j], s2a[j]);
                if (sc < rmin[i] || (sc == rmin[i] && nca[j] < ridx[i])) {
                    rmin[i] = sc; ridx[i] = nca[j];
                }
            }
    }
    __syncthreads();
    float* redv = (float*)Xs;
    int* redi = (int*)Bs;
#pragma unroll
    for (int i = 0; i < 8; ++i) {
        int mrow = (i < 4) ? (ty * 4 + i) : (64 + ty * 4 + (i - 4));
        redv[mrow * 16 + tx] = rmin[i];
        redi[mrow * 16 + tx] = ridx[i];
    }
    __syncthreads();
    if (tid < SBM) {
        float best = redv[tid * 16];
        int bi = redi[tid * 16];
#pragma unroll
        for (int t = 1; t < 16; ++t) {
            float v = redv[tid * 16 + t];
            int ix = redi[tid * 16 + t];
            if (v < best || (v == best && ix < bi)) { best = v; bi = ix; }
        }
        pvals[(size_t)(m0 + tid) * SGY + by] = best;
        pidx[(size_t)(m0 + tid) * SGY + by] = bi;
    }
}

__global__ __launch_bounds__(64) void finalize_f32(const float* __restrict__ pvals,
                                                   const int* __restrict__ pidx,
                                                   const int* __restrict__ labels,
                                                   const int* __restrict__ ncp,
                                                   int* __restrict__ out) {
    const int b = blockIdx.x, lane = threadIdx.x;
    float v = pvals[(size_t)b * SGY + lane];
    int ix = pidx[(size_t)b * SGY + lane];
#pragma unroll
    for (int off = 32; off > 0; off >>= 1) {
        float ov = __shfl_xor(v, off);
        int oi = __shfl_xor(ix, off);
        if (ov < v || (ov == v && oi < ix)) { v = ov; ix = oi; }
    }
    bool is64 = true;
    for (int i = 1; i < 128; i += 2)
        if (labels[i] != 0) { is64 = false; break; }
    const int lbl = is64 ? labels[2 * ix] : labels[ix];
    const int nc = ncp[0];
    for (int c = lane; c < nc; c += 64)
        out[b * nc + c] = (c == lbl) ? 1 : 0;
}

// ---------------------------------------------------------------------------
extern "C" void kernel_launch(void* const* d_in, const int* in_sizes, int n_in,
                              void* d_out, int out_size, void* d_ws, size_t ws_size,
                              hipStream_t stream) {
    const float* x      = (const float*)d_in[0];
    const float* sup    = (const float*)d_in[1];
    const int*   labels = (const int*)d_in[2];
    const int*   ncp    = (const int*)d_in[3];
    int* out = (int*)d_out;

    // fast-path workspace layout
    char* p = (char*)d_ws;
    float* s2      = (float*)p;           p += (size_t)NS * 4;
    float* pv1     = (float*)p;           p += (size_t)BQ * GY * 4;
    float* pv2     = (float*)p;           p += (size_t)BQ * GY * 4;
    int*   pi1     = (int*)p;             p += (size_t)BQ * GY * 4;
    int*   fb_cnt  = (int*)p;             p += 256;   // padded
    int*   fb_list = (int*)p;             p += (size_t)BQ * 4;
    float* fb_v    = (float*)p;           p += (size_t)BQ * FBCH * 4;
    int*   fb_i    = (int*)p;             p += (size_t)BQ * FBCH * 4;
    f16*   xh      = (f16*)p;             p += (size_t)BQ * DIM * 2;
    f16*   xl      = (f16*)p;             p += (size_t)BQ * DIM * 2;
    f16*   sh      = (f16*)p;             p += (size_t)NS * DIM * 2;
    const size_t need = (size_t)(p - (char*)d_ws);

    if (ws_size >= need) {
        convert_kernel<<<NROWS / 4, 256, 0, stream>>>(x, sup, xh, xl, sh, s2, fb_cnt);
        dim3 grid(BQ / BM, GY);
        knn_mfma<<<grid, 256, 0, stream>>>(xh, xl, sh, s2, pv1, pv2, pi1);
        finalize2<<<BQ, 128, 0, stream>>>(pv1, pv2, pi1, labels, ncp, out, fb_cnt, fb_list);
        dim3 fbgrid(FBCH, 64);
        fallback_scan<<<fbgrid, 256, 0, stream>>>(x, sup, s2, fb_cnt, fb_list, fb_v, fb_i);
        fallback_merge<<<64, 64, 0, stream>>>(fb_cnt, fb_list, fb_v, fb_i, labels, ncp, out);
    } else {
        // slow path: proven fp32 pipeline (R3)
        float* ss2   = (float*)d_ws;
        float* pvals = ss2 + NS;
        int*   pidx  = (int*)(pvals + (size_t)BQ * SGY);
        s2_kernel<<<NS / 4, 256, 0, stream>>>(sup, ss2);
        dim3 grid(BQ / SBM, SGY);
        knn_f32<<<grid, 256, 0, stream>>>(x, sup, ss2, pvals, pidx);
        finalize_f32<<<BQ, 64, 0, stream>>>(pvals, pidx, labels, ncp, out);
    }
}

// Round 9
// 255.949 us; speedup vs baseline: 1.1593x; 1.0397x over previous
//
#include <hip/hip_runtime.h>

// ---------------------------------------------------------------------------
// Problem constants
#define BQ 2048
#define NS 32768
#define DIM 256
#define NROWS (NS + BQ)

// Fast-path (MFMA) tiling: block = 256 queries x 128 supports, 4 waves,
// wave = 64q x 128s (4 A-frags x 8 B-frags, acc = 128 AGPR). NTILES=1.
#define BMQ 256                // queries per block
#define BNS 128                // supports per block
#define BK 32                  // K per stage
#define NST (DIM / BK)         // 8 pipeline stages (8 barriers/block)
#define GY (NS / BNS)          // 256 chunks per query
// Certification: score = s2 - 2*(xh . sh), both RTN f16. err std ~6.8e-3;
// EPS = 0.08 ~ 8 sigma of pair-err. Expected flags ~18 of 2048 (gap density
// measured R4: 3 flags @ 0.02). Ties/near-ties -> exact fp32 fallback.
#define EPS 0.08f
#define FBCH 256               // fallback chunks per query (128 rows each)

typedef _Float16 f16;
typedef _Float16 f16x4 __attribute__((ext_vector_type(4)));
typedef _Float16 f16x8 __attribute__((ext_vector_type(8)));
typedef float    f32x4 __attribute__((ext_vector_type(4)));

// ---------------------------------------------------------------------------
// global->LDS DMA, 16B/lane; LDS dest = wave-uniform base + lane*16.
// Per-lane source address carries the XOR swizzle (R7-verified: 0 conflicts).
// ---------------------------------------------------------------------------
__device__ __forceinline__ void gload16(const f16* g, f16* l) {
    __builtin_amdgcn_global_load_lds(
        (const __attribute__((address_space(1))) unsigned int*)g,
        (__attribute__((address_space(3))) unsigned int*)l, 16, 0, 0);
}

// Swizzled fragment pointer: rows of 32 f16 (64 B), cell q stored at
// q ^ ((row>>1)&3).
__device__ __forceinline__ const f16x8* fragp(const f16* base, int row, int q) {
    return (const f16x8*)(base + row * 32 + ((q ^ ((row >> 1) & 3)) << 3));
}

// ---------------------------------------------------------------------------
// Kernel 1: x -> f16 xh, sup -> f16 sh, s2 exact fp32. One wave per row.
// Block 0 thread 0 zeroes fb_cnt.
// ---------------------------------------------------------------------------
__global__ __launch_bounds__(256) void convert_kernel(
    const float* __restrict__ x, const float* __restrict__ sup,
    f16* __restrict__ xh, f16* __restrict__ sh,
    float* __restrict__ s2, int* __restrict__ fb_cnt) {
    if (blockIdx.x == 0 && threadIdx.x == 0) *fb_cnt = 0;
    const int wave = threadIdx.x >> 6, lane = threadIdx.x & 63;
    const int row = blockIdx.x * 4 + wave;
    if (row < NS) {
        float4 v = ((const float4*)(sup + (size_t)row * DIM))[lane];
        f16x4 hi;
        hi[0] = (f16)v.x; hi[1] = (f16)v.y; hi[2] = (f16)v.z; hi[3] = (f16)v.w;
        *(f16x4*)(sh + (size_t)row * DIM + lane * 4) = hi;
        float sum = v.x * v.x + v.y * v.y + v.z * v.z + v.w * v.w;
#pragma unroll
        for (int off = 32; off > 0; off >>= 1) sum += __shfl_xor(sum, off);
        if (lane == 0) s2[row] = sum;
    } else {
        const int q = row - NS;
        float4 v = ((const float4*)(x + (size_t)q * DIM))[lane];
        f16x4 hi;
        hi[0] = (f16)v.x; hi[1] = (f16)v.y; hi[2] = (f16)v.z; hi[3] = (f16)v.w;
        *(f16x4*)(xh + (size_t)q * DIM + lane * 4) = hi;
    }
}

// ---------------------------------------------------------------------------
// Kernel 2: single-term f16 MFMA GEMM + certified top-2 argmin.
// R9: 256x128 block tile, one support tile per block (8 barriers total),
// 24 DMA calls/stage split 6/wave with precomputed incremental pointers.
// LDS: 2 x (Xh 16KB + Sh 8KB) = 48 KB.
// ---------------------------------------------------------------------------
__global__ __launch_bounds__(256) void knn_mfma(
    const f16* __restrict__ xh, const f16* __restrict__ sh,
    const float* __restrict__ s2g,
    float* __restrict__ pv1, float* __restrict__ pv2, int* __restrict__ pi1) {
    __shared__ f16 T[2][12288];   // [buf][Xh 8192 f16 | Sh 4096 f16] = 48 KB

    const int tid  = threadIdx.x;
    const int lane = tid & 63, wid = tid >> 6;
    const int l16  = lane & 15, quad = lane >> 4;
    const int m0   = blockIdx.x * BMQ;
    const int n0   = blockIdx.y * BNS;

    // DMA per-lane swizzled source offset (one call = 16 rows x 32 f16)
    const int rl = lane >> 2;
    const int qs = (lane & 3) ^ ((rl >> 1) & 3);
    const size_t srcoff = (size_t)rl * DIM + qs * 8;

    // 24 calls/stage: c<16 -> Xh row c*16, else Sh row (c-16)*16.
    // Wave w owns c = 6w..6w+5. Pointers precomputed once (k0 added per stage).
    const f16* pc[6];
    int dst[6];
#pragma unroll
    for (int i = 0; i < 6; ++i) {
        const int c = wid * 6 + i;
        if (c < 16) pc[i] = xh + (size_t)(m0 + c * 16) * DIM + srcoff;
        else        pc[i] = sh + (size_t)(n0 + (c - 16) * 16) * DIM + srcoff;
        dst[i] = c * 512;
    }

    f32x4 acc[4][8];
#pragma unroll
    for (int fi = 0; fi < 4; ++fi)
#pragma unroll
        for (int fj = 0; fj < 8; ++fj) acc[fi][fj] = (f32x4){0.f, 0.f, 0.f, 0.f};

    // prologue prefetch of stage 0
    {
        f16* lb = &T[0][0];
#pragma unroll
        for (int i = 0; i < 6; ++i) gload16(pc[i], lb + dst[i]);
    }

    for (int s = 0; s < NST; ++s) {
        __syncthreads();                  // drains DMA for stage s
        if (s + 1 < NST) {
            f16* lb = &T[(s + 1) & 1][0];
            const int k0 = (s + 1) * BK;
#pragma unroll
            for (int i = 0; i < 6; ++i) gload16(pc[i] + k0, lb + dst[i]);
        }
        const f16* Tb = &T[s & 1][0];

        f16x8 A[4];
#pragma unroll
        for (int fi = 0; fi < 4; ++fi)
            A[fi] = *fragp(Tb, wid * 64 + fi * 16 + l16, quad);
#pragma unroll
        for (int fj = 0; fj < 8; ++fj) {
            f16x8 B = *fragp(Tb + 8192, fj * 16 + l16, quad);
#pragma unroll
            for (int fi = 0; fi < 4; ++fi)
                acc[fi][fj] = __builtin_amdgcn_mfma_f32_16x16x32_f16(A[fi], B, acc[fi][fj], 0, 0, 0);
        }
    }

    // epilogue: per-slot top-2 over 8 cols, then 16-lane merge, write partials
    float s2v[8];
#pragma unroll
    for (int fj = 0; fj < 8; ++fj) s2v[fj] = s2g[n0 + fj * 16 + l16];
#pragma unroll
    for (int fi = 0; fi < 4; ++fi)
#pragma unroll
        for (int rg = 0; rg < 4; ++rg) {
            float bv1 = 3.4e38f, bv2 = 3.4e38f; int bi = 0;
#pragma unroll
            for (int fj = 0; fj < 8; ++fj) {
                float s = fmaf(-2.f, acc[fi][fj][rg], s2v[fj]);
                bv2 = fminf(bv2, fmaxf(bv1, s));
                bi  = (s < bv1) ? (n0 + fj * 16 + l16) : bi;
                bv1 = fminf(bv1, s);
            }
#pragma unroll
            for (int m = 1; m < 16; m <<= 1) {
                float ov1 = __shfl_xor(bv1, m);
                float ov2 = __shfl_xor(bv2, m);
                int   oi  = __shfl_xor(bi, m);
                float nb2 = fminf(fminf(bv2, ov2), fmaxf(bv1, ov1));
                bi  = (ov1 < bv1) ? oi : bi;
                bv1 = fminf(bv1, ov1);
                bv2 = nb2;
            }
            if (l16 == 0) {
                const int row = m0 + wid * 64 + fi * 16 + quad * 4 + rg;
                pv1[(size_t)row * GY + blockIdx.y] = bv1;
                pv2[(size_t)row * GY + blockIdx.y] = bv2;
                pi1[(size_t)row * GY + blockIdx.y] = bi;
            }
        }
}

// ---------------------------------------------------------------------------
// Kernel 3: merge GY chunk-top2s; one-hot; flag + list uncertified queries.
// ---------------------------------------------------------------------------
__global__ __launch_bounds__(128) void finalize2(
    const float* __restrict__ pv1, const float* __restrict__ pv2,
    const int* __restrict__ pi1, const int* __restrict__ labels,
    const int* __restrict__ ncp, int* __restrict__ out,
    int* __restrict__ fb_cnt, int* __restrict__ fb_list) {
    const int q = blockIdx.x, tid = threadIdx.x;
    __shared__ int s_label;
    if (tid < 64) {
        float bv1 = 3.4e38f, bv2 = 3.4e38f; int bi = 0;
        for (int t = tid; t < GY; t += 64) {
            float ov1 = pv1[(size_t)q * GY + t];
            float ov2 = pv2[(size_t)q * GY + t];
            int   oi  = pi1[(size_t)q * GY + t];
            float nb2 = fminf(fminf(bv2, ov2), fmaxf(bv1, ov1));
            bi  = (ov1 < bv1) ? oi : bi;
            bv1 = fminf(bv1, ov1);
            bv2 = nb2;
        }
#pragma unroll
        for (int m = 1; m < 64; m <<= 1) {
            float ov1 = __shfl_xor(bv1, m);
            float ov2 = __shfl_xor(bv2, m);
            int   oi  = __shfl_xor(bi, m);
            float nb2 = fminf(fminf(bv2, ov2), fmaxf(bv1, ov1));
            bi  = (ov1 < bv1) ? oi : bi;
            bv1 = fminf(bv1, ov1);
            bv2 = nb2;
        }
        if (tid == 0) {
            if (bv2 - bv1 <= EPS) {
                int slot = atomicAdd(fb_cnt, 1);
                fb_list[slot] = q;
            }
            bool is64 = true;
            for (int i = 1; i < 128; i += 2)
                if (labels[i] != 0) { is64 = false; break; }
            s_label = is64 ? labels[2 * bi] : labels[bi];
        }
    }
    __syncthreads();
    const int nc = ncp[0], lbl = s_label;
    for (int c = tid; c < nc; c += 128)
        out[q * nc + c] = (c == lbl) ? 1 : 0;
}

// ---------------------------------------------------------------------------
// Kernel 4: exact fp32 rescan for listed queries, parallel + coalesced.
// R9: block covers only 128 rows (wave = 32 rows, independent iterations)
// so the dependent-load chain is short; 256 chunk-partials per query.
// ---------------------------------------------------------------------------
__global__ __launch_bounds__(256) void fallback_scan(
    const float* __restrict__ x, const float* __restrict__ sup,
    const float* __restrict__ s2, const int* __restrict__ fb_cnt,
    const int* __restrict__ fb_list,
    float* __restrict__ fb_v, int* __restrict__ fb_i) {
    const int nslots = *fb_cnt;
    const int chunk = blockIdx.x;          // 0..FBCH-1, 128 rows each
    const int tid = threadIdx.x, lane = tid & 63, w = tid >> 6;
    __shared__ float wv[4];
    __shared__ int   wi[4];
    for (int slot = blockIdx.y; slot < nslots; slot += gridDim.y) {
        const int q = fb_list[slot];
        const float4 xv = ((const float4*)(x + (size_t)q * DIM))[lane];
        float best = 3.4e38f; int bi = 0;
        const int base = chunk * 128 + w * 32;
#pragma unroll 4
        for (int r = 0; r < 32; ++r) {
            const int n = base + r;
            float4 sv = ((const float4*)(sup + (size_t)n * DIM))[lane];
            float d = fmaf(sv.x, xv.x,
                      fmaf(sv.y, xv.y,
                      fmaf(sv.z, xv.z, sv.w * xv.w)));
#pragma unroll
            for (int m = 32; m > 0; m >>= 1) d += __shfl_xor(d, m);
            float sc = s2[n] - 2.f * d;
            if (sc < best) { best = sc; bi = n; }   // ascending n, strict <
        }
        if (lane == 0) { wv[w] = best; wi[w] = bi; }
        __syncthreads();
        if (tid == 0) {
            float bv = wv[0]; int bx = wi[0];
#pragma unroll
            for (int t = 1; t < 4; ++t)
                if (wv[t] < bv || (wv[t] == bv && wi[t] < bx)) { bv = wv[t]; bx = wi[t]; }
            fb_v[(size_t)q * FBCH + chunk] = bv;
            fb_i[(size_t)q * FBCH + chunk] = bx;
        }
        __syncthreads();
    }
}

// ---------------------------------------------------------------------------
// Kernel 5: merge FBCH partials for listed queries, rewrite one-hot.
// ---------------------------------------------------------------------------
__global__ __launch_bounds__(64) void fallback_merge(
    const int* __restrict__ fb_cnt, const int* __restrict__ fb_list,
    const float* __restrict__ fb_v, const int* __restrict__ fb_i,
    const int* __restrict__ labels, const int* __restrict__ ncp,
    int* __restrict__ out) {
    const int nslots = *fb_cnt;
    const int lane = threadIdx.x;
    for (int slot = blockIdx.x; slot < nslots; slot += gridDim.x) {
        const int q = fb_list[slot];
        float v = 3.4e38f; int ix = 0x7fffffff;
        for (int t = lane; t < FBCH; t += 64) {
            float ov = fb_v[(size_t)q * FBCH + t];
            int   oi = fb_i[(size_t)q * FBCH + t];
            if (ov < v || (ov == v && oi < ix)) { v = ov; ix = oi; }
        }
#pragma unroll
        for (int m = 1; m < 64; m <<= 1) {
            float ov = __shfl_xor(v, m);
            int   oi = __shfl_xor(ix, m);
            if (ov < v || (ov == v && oi < ix)) { v = ov; ix = oi; }
        }
        bool is64 = true;
        for (int i = 1; i < 128; i += 2)
            if (labels[i] != 0) { is64 = false; break; }
        const int lbl = is64 ? labels[2 * ix] : labels[ix];
        const int nc = ncp[0];
        for (int c = lane; c < nc; c += 64)
            out[q * nc + c] = (c == lbl) ? 1 : 0;
    }
}

// ===========================================================================
// Slow path (ws too small): proven R3 fp32 kernels.
// ===========================================================================
#define SBM 128
#define SBN 128
#define SBK 16
#define SNT 4
#define SGY (NS / (SBN * SNT))
#define SLDT (SBM + 4)

__global__ __launch_bounds__(256) void s2_kernel(const float* __restrict__ s,
                                                 float* __restrict__ s2) {
    int wave = threadIdx.x >> 6, lane = threadIdx.x & 63;
    int row = blockIdx.x * 4 + wave;
    const float4* p = (const float4*)(s + (size_t)row * DIM);
    float4 v = p[lane];
    float sum = v.x * v.x + v.y * v.y + v.z * v.z + v.w * v.w;
#pragma unroll
    for (int off = 32; off > 0; off >>= 1) sum += __shfl_xor(sum, off);
    if (lane == 0) s2[row] = sum;
}

__global__ __launch_bounds__(256) void knn_f32(const float* __restrict__ x,
                                               const float* __restrict__ sup,
                                               const float* __restrict__ s2g,
                                               float* __restrict__ pvals,
                                               int* __restrict__ pidx) {
    __shared__ float Xs[SBK][SLDT];
    __shared__ float Bs[SBK][SLDT];
    const int tid = threadIdx.x;
    const int tx = tid & 15, ty = tid >> 4;
    const int m0 = blockIdx.x * SBM, by = blockIdx.y;
    const int srow = tid >> 2, skq = (tid & 3) * 4;
    float rmin[8]; int ridx[8];
#pragma unroll
    for (int i = 0; i < 8; ++i) { rmin[i] = 3.4e38f; ridx[i] = 0x7fffffff; }
    const float* xr0 = x + (size_t)(m0 + srow) * DIM + skq;
    const float* xr1 = x + (size_t)(m0 + 64 + srow) * DIM + skq;
    for (int nt = 0; nt < SNT; ++nt) {
        const int n0 = (by * SNT + nt) * SBN;
        const float* sr0 = sup + (size_t)(n0 + srow) * DIM + skq;
        const float* sr1 = sup + (size_t)(n0 + 64 + srow) * DIM + skq;
        float acc[8][8];
#pragma unroll
        for (int i = 0; i < 8; ++i)
#pragma unroll
            for (int j = 0; j < 8; ++j) acc[i][j] = 0.0f;
        for (int kt = 0; kt < DIM / SBK; ++kt) {
            const int k0 = kt * SBK;
            float4 xv0 = *(const float4*)(xr0 + k0);
            float4 xv1 = *(const float4*)(xr1 + k0);
            float4 sv0 = *(const float4*)(sr0 + k0);
            float4 sv1 = *(const float4*)(sr1 + k0);
            __syncthreads();
            Xs[skq + 0][srow] = xv0.x; Xs[skq + 1][srow] = xv0.y;
            Xs[skq + 2][srow] = xv0.z; Xs[skq + 3][srow] = xv0.w;
            Xs[skq + 0][64 + srow] = xv1.x; Xs[skq + 1][64 + srow] = xv1.y;
            Xs[skq + 2][64 + srow] = xv1.z; Xs[skq + 3][64 + srow] = xv1.w;
            Bs[skq + 0][srow] = sv0.x; Bs[skq + 1][srow] = sv0.y;
            Bs[skq + 2][srow] = sv0.z; Bs[skq + 3][srow] = sv0.w;
            Bs[skq + 0][64 + srow] = sv1.x; Bs[skq + 1][64 + srow] = sv1.y;
            Bs[skq + 2][64 + srow] = sv1.z; Bs[skq + 3][64 + srow] = sv1.w;
            __syncthreads();
#pragma unroll
            for (int k = 0; k < SBK; ++k) {
                float4 a0 = *(const float4*)&Xs[k][ty * 4];
                float4 a1 = *(const float4*)&Xs[k][64 + ty * 4];
                float4 b0 = *(const float4*)&Bs[k][tx * 4];
                float4 b1 = *(const float4*)&Bs[k][64 + tx * 4];
                float a[8] = {a0.x, a0.y, a0.z, a0.w, a1.x, a1.y, a1.z, a1.w};
                float b[8] = {b0.x, b0.y, b0.z, b0.w, b1.x, b1.y, b1.z, b1.w};
#pragma unroll
                for (int i = 0; i < 8; ++i)
#pragma unroll
                    for (int j = 0; j < 8; ++j)
                        acc[i][j] = fmaf(a[i], b[j], acc[i][j]);
            }
        }
        const int nb0 = n0 + tx * 4, nb1 = n0 + 64 + tx * 4;
        float4 s20 = *(const float4*)(s2g + nb0);
        float4 s21 = *(const float4*)(s2g + nb1);
        float s2a[8] = {s20.x, s20.y, s20.z, s20.w, s21.x, s21.y, s21.z, s21.w};
        int nca[8] = {nb0, nb0 + 1, nb0 + 2, nb0 + 3, nb1, nb1 + 1, nb1 + 2, nb1 + 3};
#pragma unroll
        for (int i = 0; i < 8; ++i)
#pragma unroll
            for (int j = 0; j < 8; ++j) {
                float sc = fmaf(-2.0f, acc[i][j], s2a[j]);
                if (sc < rmin[i] || (sc == rmin[i] && nca[j] < ridx[i])) {
                    rmin[i] = sc; ridx[i] = nca[j];
                }
            }
    }
    __syncthreads();
    float* redv = (float*)Xs;
    int* redi = (int*)Bs;
#pragma unroll
    for (int i = 0; i < 8; ++i) {
        int mrow = (i < 4) ? (ty * 4 + i) : (64 + ty * 4 + (i - 4));
        redv[mrow * 16 + tx] = rmin[i];
        redi[mrow * 16 + tx] = ridx[i];
    }
    __syncthreads();
    if (tid < SBM) {
        float best = redv[tid * 16];
        int bi = redi[tid * 16];
#pragma unroll
        for (int t = 1; t < 16; ++t) {
            float v = redv[tid * 16 + t];
            int ix = redi[tid * 16 + t];
            if (v < best || (v == best && ix < bi)) { best = v; bi = ix; }
        }
        pvals[(size_t)(m0 + tid) * SGY + by] = best;
        pidx[(size_t)(m0 + tid) * SGY + by] = bi;
    }
}

__global__ __launch_bounds__(64) void finalize_f32(const float* __restrict__ pvals,
                                                   const int* __restrict__ pidx,
                                                   const int* __restrict__ labels,
                                                   const int* __restrict__ ncp,
                                                   int* __restrict__ out) {
    const int b = blockIdx.x, lane = threadIdx.x;
    float v = pvals[(size_t)b * SGY + lane];
    int ix = pidx[(size_t)b * SGY + lane];
#pragma unroll
    for (int off = 32; off > 0; off >>= 1) {
        float ov = __shfl_xor(v, off);
        int oi = __shfl_xor(ix, off);
        if (ov < v || (ov == v && oi < ix)) { v = ov; ix = oi; }
    }
    bool is64 = true;
    for (int i = 1; i < 128; i += 2)
        if (labels[i] != 0) { is64 = false; break; }
    const int lbl = is64 ? labels[2 * ix] : labels[ix];
    const int nc = ncp[0];
    for (int c = lane; c < nc; c += 64)
        out[b * nc + c] = (c == lbl) ? 1 : 0;
}

// ---------------------------------------------------------------------------
extern "C" void kernel_launch(void* const* d_in, const int* in_sizes, int n_in,
                              void* d_out, int out_size, void* d_ws, size_t ws_size,
                              hipStream_t stream) {
    const float* x      = (const float*)d_in[0];
    const float* sup    = (const float*)d_in[1];
    const int*   labels = (const int*)d_in[2];
    const int*   ncp    = (const int*)d_in[3];
    int* out = (int*)d_out;

    // fast-path workspace layout (~27 MB)
    char* p = (char*)d_ws;
    float* s2      = (float*)p;           p += (size_t)NS * 4;
    float* pv1     = (float*)p;           p += (size_t)BQ * GY * 4;
    float* pv2     = (float*)p;           p += (size_t)BQ * GY * 4;
    int*   pi1     = (int*)p;             p += (size_t)BQ * GY * 4;
    int*   fb_cnt  = (int*)p;             p += 256;   // padded
    int*   fb_list = (int*)p;             p += (size_t)BQ * 4;
    float* fb_v    = (float*)p;           p += (size_t)BQ * FBCH * 4;
    int*   fb_i    = (int*)p;             p += (size_t)BQ * FBCH * 4;
    f16*   xh      = (f16*)p;             p += (size_t)BQ * DIM * 2;
    f16*   sh      = (f16*)p;             p += (size_t)NS * DIM * 2;
    const size_t need = (size_t)(p - (char*)d_ws);

    if (ws_size >= need) {
        convert_kernel<<<NROWS / 4, 256, 0, stream>>>(x, sup, xh, sh, s2, fb_cnt);
        dim3 grid(BQ / BMQ, GY);
        knn_mfma<<<grid, 256, 0, stream>>>(xh, sh, s2, pv1, pv2, pi1);
        finalize2<<<BQ, 128, 0, stream>>>(pv1, pv2, pi1, labels, ncp, out, fb_cnt, fb_list);
        dim3 fbgrid(FBCH, 64);
        fallback_scan<<<fbgrid, 256, 0, stream>>>(x, sup, s2, fb_cnt, fb_list, fb_v, fb_i);
        fallback_merge<<<64, 64, 0, stream>>>(fb_cnt, fb_list, fb_v, fb_i, labels, ncp, out);
    } else {
        // slow path: proven fp32 pipeline (R3)
        float* ss2   = (float*)d_ws;
        float* pvals = ss2 + NS;
        int*   pidx  = (int*)(pvals + (size_t)BQ * SGY);
        s2_kernel<<<NS / 4, 256, 0, stream>>>(sup, ss2);
        dim3 grid(BQ / SBM, SGY);
        knn_f32<<<grid, 256, 0, stream>>>(x, sup, ss2, pvals, pidx);
        finalize_f32<<<BQ, 64, 0, stream>>>(pvals, pidx, labels, ncp, out);
    }
}

// Round 10
// 158.909 us; speedup vs baseline: 1.8673x; 1.6107x over previous
//
#include <hip/hip_runtime.h>

// ---------------------------------------------------------------------------
// Problem constants
#define BQ 2048
#define NS 32768
#define DIM 256
#define NROWS (NS + BQ)

// Fast-path (MFMA) tiling: block = 128q x 128s, 4 waves, wave = 32q x 128s
// (2 A-frags x 8 B-frags, acc = 64 AGPR). R10: back from 256q (R9's 1 wave/
// SIMD trap: VGPR 144 + 128 AGPR = 272 -> occupancy 10%).
#define BMQ 128                // queries per block
#define BNS 128                // supports per block
#define BK 32                  // K per stage
#define NST (DIM / BK)         // 8 pipeline stages
#define GY (NS / BNS)          // 256 chunks per query
// Certification: score = s2 - 2*(xh . sh), RTN f16. EPS = 0.08 ~ 8 sigma of
// per-pair error (validated: absmax 0 at R9). Flagged queries are resolved by
// the candidate-chunk exact rescan (only chunks with pv1 <= qbest+EPS can
// contain the exact argmin: |approx-exact| <= EPS/2 per score).
#define EPS 0.08f
#define FBCH GY                // fallback chunk granularity == partial chunks

typedef _Float16 f16;
typedef _Float16 f16x4 __attribute__((ext_vector_type(4)));
typedef _Float16 f16x8 __attribute__((ext_vector_type(8)));
typedef float    f32x4 __attribute__((ext_vector_type(4)));

// ---------------------------------------------------------------------------
// global->LDS DMA, 16B/lane; LDS dest = wave-uniform base + lane*16.
// Per-lane source address carries the XOR swizzle (R7-verified: 0 conflicts).
// ---------------------------------------------------------------------------
__device__ __forceinline__ void gload16(const f16* g, f16* l) {
    __builtin_amdgcn_global_load_lds(
        (const __attribute__((address_space(1))) unsigned int*)g,
        (__attribute__((address_space(3))) unsigned int*)l, 16, 0, 0);
}

// Swizzled fragment pointer: rows of 32 f16 (64 B), cell q stored at
// q ^ ((row>>1)&3).
__device__ __forceinline__ const f16x8* fragp(const f16* base, int row, int q) {
    return (const f16x8*)(base + row * 32 + ((q ^ ((row >> 1) & 3)) << 3));
}

// ---------------------------------------------------------------------------
// Kernel 1: x -> f16 xh, sup -> f16 sh, s2 exact fp32. One wave per row.
// Block 0 thread 0 zeroes fb_cnt.
// ---------------------------------------------------------------------------
__global__ __launch_bounds__(256) void convert_kernel(
    const float* __restrict__ x, const float* __restrict__ sup,
    f16* __restrict__ xh, f16* __restrict__ sh,
    float* __restrict__ s2, int* __restrict__ fb_cnt) {
    if (blockIdx.x == 0 && threadIdx.x == 0) *fb_cnt = 0;
    const int wave = threadIdx.x >> 6, lane = threadIdx.x & 63;
    const int row = blockIdx.x * 4 + wave;
    if (row < NS) {
        float4 v = ((const float4*)(sup + (size_t)row * DIM))[lane];
        f16x4 hi;
        hi[0] = (f16)v.x; hi[1] = (f16)v.y; hi[2] = (f16)v.z; hi[3] = (f16)v.w;
        *(f16x4*)(sh + (size_t)row * DIM + lane * 4) = hi;
        float sum = v.x * v.x + v.y * v.y + v.z * v.z + v.w * v.w;
#pragma unroll
        for (int off = 32; off > 0; off >>= 1) sum += __shfl_xor(sum, off);
        if (lane == 0) s2[row] = sum;
    } else {
        const int q = row - NS;
        float4 v = ((const float4*)(x + (size_t)q * DIM))[lane];
        f16x4 hi;
        hi[0] = (f16)v.x; hi[1] = (f16)v.y; hi[2] = (f16)v.z; hi[3] = (f16)v.w;
        *(f16x4*)(xh + (size_t)q * DIM + lane * 4) = hi;
    }
}

// ---------------------------------------------------------------------------
// Kernel 2: single-term f16 MFMA GEMM + top-2 argmin. 128x128 block tile,
// double-buffered DMA (4 calls/wave/stage), 8 barriers/block, grid 16x256.
// ---------------------------------------------------------------------------
__global__ __launch_bounds__(256) void knn_mfma(
    const f16* __restrict__ xh, const f16* __restrict__ sh,
    const float* __restrict__ s2g,
    float* __restrict__ pv1, float* __restrict__ pv2, int* __restrict__ pi1) {
    __shared__ f16 T[2][2][BMQ * 32];   // [buf][X|S][row*32], 32 KB total

    const int tid  = threadIdx.x;
    const int lane = tid & 63, wid = tid >> 6;
    const int l16  = lane & 15, quad = lane >> 4;
    const int m0   = blockIdx.x * BMQ;
    const int n0   = blockIdx.y * BNS;

    // DMA per-lane swizzled source offset (one call = 16 rows x 32 f16 = 1KB)
    const int rl = lane >> 2;
    const int qs = (lane & 3) ^ ((rl >> 1) & 3);
    const size_t srcoff = (size_t)rl * DIM + qs * 8;

    // wave w stages X rows 32w..32w+31 and S rows 32w..32w+31 (2 calls each)
    const f16* px0 = xh + (size_t)(m0 + wid * 32) * DIM + srcoff;
    const f16* px1 = px0 + (size_t)16 * DIM;
    const f16* ps0 = sh + (size_t)(n0 + wid * 32) * DIM + srcoff;
    const f16* ps1 = ps0 + (size_t)16 * DIM;
    const int dX = wid * 1024;          // f16 offset: row 32w

    f32x4 acc[2][8];
#pragma unroll
    for (int fi = 0; fi < 2; ++fi)
#pragma unroll
        for (int fj = 0; fj < 8; ++fj) acc[fi][fj] = (f32x4){0.f, 0.f, 0.f, 0.f};

    // prologue prefetch stage 0
    gload16(px0, &T[0][0][dX]);
    gload16(px1, &T[0][0][dX + 512]);
    gload16(ps0, &T[0][1][dX]);
    gload16(ps1, &T[0][1][dX + 512]);

    for (int s = 0; s < NST; ++s) {
        __syncthreads();                  // drains DMA for stage s
        if (s + 1 < NST) {
            const int b = (s + 1) & 1, k0 = (s + 1) * BK;
            gload16(px0 + k0, &T[b][0][dX]);
            gload16(px1 + k0, &T[b][0][dX + 512]);
            gload16(ps0 + k0, &T[b][1][dX]);
            gload16(ps1 + k0, &T[b][1][dX + 512]);
        }
        const f16* TX = &T[s & 1][0][0];
        const f16* TS = &T[s & 1][1][0];

        f16x8 A0 = *fragp(TX, wid * 32 + l16,      quad);
        f16x8 A1 = *fragp(TX, wid * 32 + 16 + l16, quad);
#pragma unroll
        for (int fj = 0; fj < 8; ++fj) {
            f16x8 B = *fragp(TS, fj * 16 + l16, quad);
            acc[0][fj] = __builtin_amdgcn_mfma_f32_16x16x32_f16(A0, B, acc[0][fj], 0, 0, 0);
            acc[1][fj] = __builtin_amdgcn_mfma_f32_16x16x32_f16(A1, B, acc[1][fj], 0, 0, 0);
        }
    }

    // epilogue: per-slot top-2 over 8 cols, 16-lane merge, write partials
    float s2v[8];
#pragma unroll
    for (int fj = 0; fj < 8; ++fj) s2v[fj] = s2g[n0 + fj * 16 + l16];
#pragma unroll
    for (int fi = 0; fi < 2; ++fi)
#pragma unroll
        for (int rg = 0; rg < 4; ++rg) {
            float bv1 = 3.4e38f, bv2 = 3.4e38f; int bi = 0;
#pragma unroll
            for (int fj = 0; fj < 8; ++fj) {
                float s = fmaf(-2.f, acc[fi][fj][rg], s2v[fj]);
                bv2 = fminf(bv2, fmaxf(bv1, s));
                bi  = (s < bv1) ? (n0 + fj * 16 + l16) : bi;
                bv1 = fminf(bv1, s);
            }
#pragma unroll
            for (int m = 1; m < 16; m <<= 1) {
                float ov1 = __shfl_xor(bv1, m);
                float ov2 = __shfl_xor(bv2, m);
                int   oi  = __shfl_xor(bi, m);
                float nb2 = fminf(fminf(bv2, ov2), fmaxf(bv1, ov1));
                bi  = (ov1 < bv1) ? oi : bi;
                bv1 = fminf(bv1, ov1);
                bv2 = nb2;
            }
            if (l16 == 0) {
                const int row = m0 + wid * 32 + fi * 16 + quad * 4 + rg;
                pv1[(size_t)row * GY + blockIdx.y] = bv1;
                pv2[(size_t)row * GY + blockIdx.y] = bv2;
                pi1[(size_t)row * GY + blockIdx.y] = bi;
            }
        }
}

// ---------------------------------------------------------------------------
// Kernel 3: merge GY chunk-top2s; one-hot; flag + list uncertified queries;
// store qbest for the candidate-chunk fallback filter.
// ---------------------------------------------------------------------------
__global__ __launch_bounds__(128) void finalize2(
    const float* __restrict__ pv1, const float* __restrict__ pv2,
    const int* __restrict__ pi1, const int* __restrict__ labels,
    const int* __restrict__ ncp, int* __restrict__ out,
    int* __restrict__ fb_cnt, int* __restrict__ fb_list,
    float* __restrict__ qbest) {
    const int q = blockIdx.x, tid = threadIdx.x;
    __shared__ int s_label;
    if (tid < 64) {
        float bv1 = 3.4e38f, bv2 = 3.4e38f; int bi = 0;
        for (int t = tid; t < GY; t += 64) {
            float ov1 = pv1[(size_t)q * GY + t];
            float ov2 = pv2[(size_t)q * GY + t];
            int   oi  = pi1[(size_t)q * GY + t];
            float nb2 = fminf(fminf(bv2, ov2), fmaxf(bv1, ov1));
            bi  = (ov1 < bv1) ? oi : bi;
            bv1 = fminf(bv1, ov1);
            bv2 = nb2;
        }
#pragma unroll
        for (int m = 1; m < 64; m <<= 1) {
            float ov1 = __shfl_xor(bv1, m);
            float ov2 = __shfl_xor(bv2, m);
            int   oi  = __shfl_xor(bi, m);
            float nb2 = fminf(fminf(bv2, ov2), fmaxf(bv1, ov1));
            bi  = (ov1 < bv1) ? oi : bi;
            bv1 = fminf(bv1, ov1);
            bv2 = nb2;
        }
        if (tid == 0) {
            qbest[q] = bv1;
            if (bv2 - bv1 <= EPS) {
                int slot = atomicAdd(fb_cnt, 1);
                fb_list[slot] = q;
            }
            bool is64 = true;
            for (int i = 1; i < 128; i += 2)
                if (labels[i] != 0) { is64 = false; break; }
            s_label = is64 ? labels[2 * bi] : labels[bi];
        }
    }
    __syncthreads();
    const int nc = ncp[0], lbl = s_label;
    for (int c = tid; c < nc; c += 128)
        out[q * nc + c] = (c == lbl) ? 1 : 0;
}

// ---------------------------------------------------------------------------
// Kernel 4: exact fp32 rescan for listed queries — CANDIDATE CHUNKS ONLY.
// Chunk c can contain the exact argmin only if pv1[q][c] <= qbest[q] + EPS
// (per-score |approx - exact| <= EPS/2). Skipped chunks write INF partials.
// ---------------------------------------------------------------------------
__global__ __launch_bounds__(256) void fallback_scan(
    const float* __restrict__ x, const float* __restrict__ sup,
    const float* __restrict__ s2, const int* __restrict__ fb_cnt,
    const int* __restrict__ fb_list, const float* __restrict__ qbest,
    const float* __restrict__ pv1,
    float* __restrict__ fb_v, int* __restrict__ fb_i) {
    const int nslots = *fb_cnt;
    const int chunk = blockIdx.x;          // 0..FBCH-1, 128 rows each
    const int tid = threadIdx.x, lane = tid & 63, w = tid >> 6;
    __shared__ float wv[4];
    __shared__ int   wi[4];
    for (int slot = blockIdx.y; slot < nslots; slot += gridDim.y) {
        const int q = fb_list[slot];
        if (pv1[(size_t)q * GY + chunk] > qbest[q] + EPS) {
            if (tid == 0) {
                fb_v[(size_t)q * FBCH + chunk] = 3.4e38f;
                fb_i[(size_t)q * FBCH + chunk] = 0x7fffffff;
            }
            __syncthreads();
            continue;
        }
        const float4 xv = ((const float4*)(x + (size_t)q * DIM))[lane];
        float best = 3.4e38f; int bi = 0x7fffffff;
        const int base = chunk * BNS + w * 32;
#pragma unroll 4
        for (int r = 0; r < 32; ++r) {
            const int n = base + r;
            float4 sv = ((const float4*)(sup + (size_t)n * DIM))[lane];
            float d = fmaf(sv.x, xv.x,
                      fmaf(sv.y, xv.y,
                      fmaf(sv.z, xv.z, sv.w * xv.w)));
#pragma unroll
            for (int m = 32; m > 0; m >>= 1) d += __shfl_xor(d, m);
            float sc = s2[n] - 2.f * d;
            if (sc < best) { best = sc; bi = n; }   // ascending n, strict <
        }
        if (lane == 0) { wv[w] = best; wi[w] = bi; }
        __syncthreads();
        if (tid == 0) {
            float bv = wv[0]; int bx = wi[0];
#pragma unroll
            for (int t = 1; t < 4; ++t)
                if (wv[t] < bv || (wv[t] == bv && wi[t] < bx)) { bv = wv[t]; bx = wi[t]; }
            fb_v[(size_t)q * FBCH + chunk] = bv;
            fb_i[(size_t)q * FBCH + chunk] = bx;
        }
        __syncthreads();
    }
}

// ---------------------------------------------------------------------------
// Kernel 5: merge FBCH partials for listed queries, rewrite one-hot.
// ---------------------------------------------------------------------------
__global__ __launch_bounds__(64) void fallback_merge(
    const int* __restrict__ fb_cnt, const int* __restrict__ fb_list,
    const float* __restrict__ fb_v, const int* __restrict__ fb_i,
    const int* __restrict__ labels, const int* __restrict__ ncp,
    int* __restrict__ out) {
    const int nslots = *fb_cnt;
    const int lane = threadIdx.x;
    for (int slot = blockIdx.x; slot < nslots; slot += gridDim.x) {
        const int q = fb_list[slot];
        float v = 3.4e38f; int ix = 0x7fffffff;
        for (int t = lane; t < FBCH; t += 64) {
            float ov = fb_v[(size_t)q * FBCH + t];
            int   oi = fb_i[(size_t)q * FBCH + t];
            if (ov < v || (ov == v && oi < ix)) { v = ov; ix = oi; }
        }
#pragma unroll
        for (int m = 1; m < 64; m <<= 1) {
            float ov = __shfl_xor(v, m);
            int   oi = __shfl_xor(ix, m);
            if (ov < v || (ov == v && oi < ix)) { v = ov; ix = oi; }
        }
        bool is64 = true;
        for (int i = 1; i < 128; i += 2)
            if (labels[i] != 0) { is64 = false; break; }
        const int lbl = is64 ? labels[2 * ix] : labels[ix];
        const int nc = ncp[0];
        for (int c = lane; c < nc; c += 64)
            out[q * nc + c] = (c == lbl) ? 1 : 0;
    }
}

// ===========================================================================
// Slow path (ws too small): proven R3 fp32 kernels.
// ===========================================================================
#define SBM 128
#define SBN 128
#define SBK 16
#define SNT 4
#define SGY (NS / (SBN * SNT))
#define SLDT (SBM + 4)

__global__ __launch_bounds__(256) void s2_kernel(const float* __restrict__ s,
                                                 float* __restrict__ s2) {
    int wave = threadIdx.x >> 6, lane = threadIdx.x & 63;
    int row = blockIdx.x * 4 + wave;
    const float4* p = (const float4*)(s + (size_t)row * DIM);
    float4 v = p[lane];
    float sum = v.x * v.x + v.y * v.y + v.z * v.z + v.w * v.w;
#pragma unroll
    for (int off = 32; off > 0; off >>= 1) sum += __shfl_xor(sum, off);
    if (lane == 0) s2[row] = sum;
}

__global__ __launch_bounds__(256) void knn_f32(const float* __restrict__ x,
                                               const float* __restrict__ sup,
                                               const float* __restrict__ s2g,
                                               float* __restrict__ pvals,
                                               int* __restrict__ pidx) {
    __shared__ float Xs[SBK][SLDT];
    __shared__ float Bs[SBK][SLDT];
    const int tid = threadIdx.x;
    const int tx = tid & 15, ty = tid >> 4;
    const int m0 = blockIdx.x * SBM, by = blockIdx.y;
    const int srow = tid >> 2, skq = (tid & 3) * 4;
    float rmin[8]; int ridx[8];
#pragma unroll
    for (int i = 0; i < 8; ++i) { rmin[i] = 3.4e38f; ridx[i] = 0x7fffffff; }
    const float* xr0 = x + (size_t)(m0 + srow) * DIM + skq;
    const float* xr1 = x + (size_t)(m0 + 64 + srow) * DIM + skq;
    for (int nt = 0; nt < SNT; ++nt) {
        const int n0 = (by * SNT + nt) * SBN;
        const float* sr0 = sup + (size_t)(n0 + srow) * DIM + skq;
        const float* sr1 = sup + (size_t)(n0 + 64 + srow) * DIM + skq;
        float acc[8][8];
#pragma unroll
        for (int i = 0; i < 8; ++i)
#pragma unroll
            for (int j = 0; j < 8; ++j) acc[i][j] = 0.0f;
        for (int kt = 0; kt < DIM / SBK; ++kt) {
            const int k0 = kt * SBK;
            float4 xv0 = *(const float4*)(xr0 + k0);
            float4 xv1 = *(const float4*)(xr1 + k0);
            float4 sv0 = *(const float4*)(sr0 + k0);
            float4 sv1 = *(const float4*)(sr1 + k0);
            __syncthreads();
            Xs[skq + 0][srow] = xv0.x; Xs[skq + 1][srow] = xv0.y;
            Xs[skq + 2][srow] = xv0.z; Xs[skq + 3][srow] = xv0.w;
            Xs[skq + 0][64 + srow] = xv1.x; Xs[skq + 1][64 + srow] = xv1.y;
            Xs[skq + 2][64 + srow] = xv1.z; Xs[skq + 3][64 + srow] = xv1.w;
            Bs[skq + 0][srow] = sv0.x; Bs[skq + 1][srow] = sv0.y;
            Bs[skq + 2][srow] = sv0.z; Bs[skq + 3][srow] = sv0.w;
            Bs[skq + 0][64 + srow] = sv1.x; Bs[skq + 1][64 + srow] = sv1.y;
            Bs[skq + 2][64 + srow] = sv1.z; Bs[skq + 3][64 + srow] = sv1.w;
            __syncthreads();
#pragma unroll
            for (int k = 0; k < SBK; ++k) {
                float4 a0 = *(const float4*)&Xs[k][ty * 4];
                float4 a1 = *(const float4*)&Xs[k][64 + ty * 4];
                float4 b0 = *(const float4*)&Bs[k][tx * 4];
                float4 b1 = *(const float4*)&Bs[k][64 + tx * 4];
                float a[8] = {a0.x, a0.y, a0.z, a0.w, a1.x, a1.y, a1.z, a1.w};
                float b[8] = {b0.x, b0.y, b0.z, b0.w, b1.x, b1.y, b1.z, b1.w};
#pragma unroll
                for (int i = 0; i < 8; ++i)
#pragma unroll
                    for (int j = 0; j < 8; ++j)
                        acc[i][j] = fmaf(a[i], b[j], acc[i][j]);
            }
        }
        const int nb0 = n0 + tx * 4, nb1 = n0 + 64 + tx * 4;
        float4 s20 = *(const float4*)(s2g + nb0);
        float4 s21 = *(const float4*)(s2g + nb1);
        float s2a[8] = {s20.x, s20.y, s20.z, s20.w, s21.x, s21.y, s21.z, s21.w};
        int nca[8] = {nb0, nb0 + 1, nb0 + 2, nb0 + 3, nb1, nb1 + 1, nb1 + 2, nb1 + 3};
#pragma unroll
        for (int i = 0; i < 8; ++i)
#pragma unroll
            for (int j = 0; j < 8; ++j) {
                float sc = fmaf(-2.0f, acc[i][j], s2a[j]);
                if (sc < rmin[i] || (sc == rmin[i] && nca[j] < ridx[i])) {
                    rmin[i] = sc; ridx[i] = nca[j];
                }
            }
    }
    __syncthreads();
    float* redv = (float*)Xs;
    int* redi = (int*)Bs;
#pragma unroll
    for (int i = 0; i < 8; ++i) {
        int mrow = (i < 4) ? (ty * 4 + i) : (64 + ty * 4 + (i - 4));
        redv[mrow * 16 + tx] = rmin[i];
        redi[mrow * 16 + tx] = ridx[i];
    }
    __syncthreads();
    if (tid < SBM) {
        float best = redv[tid * 16];
        int bi = redi[tid * 16];
#pragma unroll
        for (int t = 1; t < 16; ++t) {
            float v = redv[tid * 16 + t];
            int ix = redi[tid * 16 + t];
            if (v < best || (v == best && ix < bi)) { best = v; bi = ix; }
        }
        pvals[(size_t)(m0 + tid) * SGY + by] = best;
        pidx[(size_t)(m0 + tid) * SGY + by] = bi;
    }
}

__global__ __launch_bounds__(64) void finalize_f32(const float* __restrict__ pvals,
                                                   const int* __restrict__ pidx,
                                                   const int* __restrict__ labels,
                                                   const int* __restrict__ ncp,
                                                   int* __restrict__ out) {
    const int b = blockIdx.x, lane = threadIdx.x;
    float v = pvals[(size_t)b * SGY + lane];
    int ix = pidx[(size_t)b * SGY + lane];
#pragma unroll
    for (int off = 32; off > 0; off >>= 1) {
        float ov = __shfl_xor(v, off);
        int oi = __shfl_xor(ix, off);
        if (ov < v || (ov == v && oi < ix)) { v = ov; ix = oi; }
    }
    bool is64 = true;
    for (int i = 1; i < 128; i += 2)
        if (labels[i] != 0) { is64 = false; break; }
    const int lbl = is64 ? labels[2 * ix] : labels[ix];
    const int nc = ncp[0];
    for (int c = lane; c < nc; c += 64)
        out[b * nc + c] = (c == lbl) ? 1 : 0;
}

// ---------------------------------------------------------------------------
extern "C" void kernel_launch(void* const* d_in, const int* in_sizes, int n_in,
                              void* d_out, int out_size, void* d_ws, size_t ws_size,
                              hipStream_t stream) {
    const float* x      = (const float*)d_in[0];
    const float* sup    = (const float*)d_in[1];
    const int*   labels = (const int*)d_in[2];
    const int*   ncp    = (const int*)d_in[3];
    int* out = (int*)d_out;

    // fast-path workspace layout (~27 MB)
    char* p = (char*)d_ws;
    float* s2      = (float*)p;           p += (size_t)NS * 4;
    float* pv1     = (float*)p;           p += (size_t)BQ * GY * 4;
    float* pv2     = (float*)p;           p += (size_t)BQ * GY * 4;
    int*   pi1     = (int*)p;             p += (size_t)BQ * GY * 4;
    int*   fb_cnt  = (int*)p;             p += 256;   // padded
    int*   fb_list = (int*)p;             p += (size_t)BQ * 4;
    float* qbest   = (float*)p;           p += (size_t)BQ * 4;
    float* fb_v    = (float*)p;           p += (size_t)BQ * FBCH * 4;
    int*   fb_i    = (int*)p;             p += (size_t)BQ * FBCH * 4;
    f16*   xh      = (f16*)p;             p += (size_t)BQ * DIM * 2;
    f16*   sh      = (f16*)p;             p += (size_t)NS * DIM * 2;
    const size_t need = (size_t)(p - (char*)d_ws);

    if (ws_size >= need) {
        convert_kernel<<<NROWS / 4, 256, 0, stream>>>(x, sup, xh, sh, s2, fb_cnt);
        dim3 grid(BQ / BMQ, GY);
        knn_mfma<<<grid, 256, 0, stream>>>(xh, sh, s2, pv1, pv2, pi1);
        finalize2<<<BQ, 128, 0, stream>>>(pv1, pv2, pi1, labels, ncp, out,
                                          fb_cnt, fb_list, qbest);
        dim3 fbgrid(FBCH, 64);
        fallback_scan<<<fbgrid, 256, 0, stream>>>(x, sup, s2, fb_cnt, fb_list,
                                                  qbest, pv1, fb_v, fb_i);
        fallback_merge<<<64, 64, 0, stream>>>(fb_cnt, fb_list, fb_v, fb_i, labels, ncp, out);
    } else {
        // slow path: proven fp32 pipeline (R3)
        float* ss2   = (float*)d_ws;
        float* pvals = ss2 + NS;
        int*   pidx  = (int*)(pvals + (size_t)BQ * SGY);
        s2_kernel<<<NS / 4, 256, 0, stream>>>(sup, ss2);
        dim3 grid(BQ / SBM, SGY);
        knn_f32<<<grid, 256, 0, stream>>>(x, sup, ss2, pvals, pidx);
        finalize_f32<<<BQ, 64, 0, stream>>>(pvals, pidx, labels, ncp, out);
    }
}